// Round 23
// baseline (263.867 us; speedup 1.0000x reference)
//
#include <hip/hip_runtime.h>

#define Bz 4
#define Tz 1024
#define Dz 1024
#define Hz 16
#define NTz (Bz*Tz)

typedef short s8v __attribute__((ext_vector_type(8)));
typedef float f4v __attribute__((ext_vector_type(4)));

__device__ __forceinline__ float bf2f(unsigned short u){
  unsigned int x = ((unsigned int)u) << 16;
  return __builtin_bit_cast(float, x);
}
__device__ __forceinline__ unsigned short f2bf(float f){
  unsigned int x = __builtin_bit_cast(unsigned int, f);
  x += 0x7fffu + ((x >> 16) & 1u);
  return (unsigned short)(x >> 16);
}
// gelu tanh-approx == x * sigmoid(1.5957691216f*(x + 0.044715f*x^3))
__device__ __forceinline__ float gelu_f(float x){
  float z = 1.5957691216057308f * (x + 0.044715f * x * x * x);
  return x / (1.0f + __expf(-z));
}
// async global->LDS, 16B per lane; lds base must be wave-uniform
__device__ __forceinline__ void gl16(const unsigned short* g, unsigned short* l){
  __builtin_amdgcn_global_load_lds(
      (const __attribute__((address_space(1))) unsigned int*)g,
      (__attribute__((address_space(3))) unsigned int*)l, 16, 0, 0);
}

// ---- head: qkv_w transpose (3072 blocks) + LN1 (4096 blocks), independent ---
__global__ __launch_bounds__(256) void k_head(const float* __restrict__ qkv_w,
    unsigned short* __restrict__ w_qkvt, const float* __restrict__ x,
    const float* __restrict__ ln1_w, const float* __restrict__ ln1_b,
    unsigned short* __restrict__ h1bf)
{
  __shared__ float tile[32][33];
  __shared__ float red[8];
  int bid = blockIdx.x, tid = threadIdx.x;
  if (bid < 3072) {
    int c0 = (bid % 96) * 32, r0 = (bid / 96) * 32;
    int tx = tid & 31, ty = tid >> 5;
    #pragma unroll
    for (int i = 0; i < 32; i += 8)
      tile[ty + i][tx] = qkv_w[(long)(r0 + ty + i) * 3072 + c0 + tx];
    __syncthreads();
    #pragma unroll
    for (int i = 0; i < 32; i += 8)
      w_qkvt[(long)(c0 + ty + i) * 1024 + r0 + tx] = f2bf(tile[tx][ty + i]);
    return;
  }
  int row = bid - 3072;
  const float4* xp = (const float4*)(x + (long)row * Dz);
  float4 v = xp[tid];
  float s  = v.x + v.y + v.z + v.w;
  float ss = v.x*v.x + v.y*v.y + v.z*v.z + v.w*v.w;
  int lane = tid & 63, wv = tid >> 6;
  #pragma unroll
  for (int off = 32; off; off >>= 1){ s += __shfl_xor(s, off); ss += __shfl_xor(ss, off); }
  if (lane == 0){ red[wv] = s; red[4 + wv] = ss; }
  __syncthreads();
  s  = red[0] + red[1] + red[2] + red[3];
  ss = red[4] + red[5] + red[6] + red[7];
  float mean = s * (1.0f / Dz);
  float var  = ss * (1.0f / Dz) - mean * mean;
  float rstd = rsqrtf(var + 1e-5f);
  float4 wg = ((const float4*)ln1_w)[tid];
  float4 bg = ((const float4*)ln1_b)[tid];
  ushort4 ov;
  ov.x = f2bf((v.x - mean) * rstd * wg.x + bg.x);
  ov.y = f2bf((v.y - mean) * rstd * wg.y + bg.y);
  ov.z = f2bf((v.z - mean) * rstd * wg.z + bg.z);
  ov.w = f2bf((v.w - mean) * rstd * wg.w + bg.w);
  *((ushort4*)(h1bf + (long)row * Dz) + tid) = ov;
}

// ---- layernorm + router fused: bf16 x2 in -> bf16 h, fp32 softmax4 ----------
__global__ __launch_bounds__(256) void k_ln_router(const unsigned short* __restrict__ x2,
    const float* __restrict__ w, const float* __restrict__ b,
    const float* __restrict__ rw, unsigned short* __restrict__ out,
    float* __restrict__ rout)
{
  int row = blockIdx.x, tid = threadIdx.x;
  ushort4 xu = *((const ushort4*)(x2 + (long)row * Dz) + tid);
  float4 v = {bf2f(xu.x), bf2f(xu.y), bf2f(xu.z), bf2f(xu.w)};
  float s  = v.x + v.y + v.z + v.w;
  float ss = v.x*v.x + v.y*v.y + v.z*v.z + v.w*v.w;
  int lane = tid & 63, wv = tid >> 6;
  #pragma unroll
  for (int off = 32; off; off >>= 1){ s += __shfl_xor(s, off); ss += __shfl_xor(ss, off); }
  __shared__ float red[8];
  if (lane == 0){ red[wv] = s; red[4 + wv] = ss; }
  __syncthreads();
  s  = red[0] + red[1] + red[2] + red[3];
  ss = red[4] + red[5] + red[6] + red[7];
  float mean = s * (1.0f / Dz);
  float var  = ss * (1.0f / Dz) - mean * mean;
  float rstd = rsqrtf(var + 1e-5f);
  float4 wg = ((const float4*)w)[tid];
  float4 bg = ((const float4*)b)[tid];
  float h0 = (v.x - mean) * rstd * wg.x + bg.x;
  float h1 = (v.y - mean) * rstd * wg.y + bg.y;
  float h2 = (v.z - mean) * rstd * wg.z + bg.z;
  float h3 = (v.w - mean) * rstd * wg.w + bg.w;
  ushort4 ov;
  ov.x = f2bf(h0); ov.y = f2bf(h1); ov.z = f2bf(h2); ov.w = f2bf(h3);
  *((ushort4*)(out + (long)row * Dz) + tid) = ov;
  // router dot-products
  int d0 = tid * 4;
  float4 r0 = *(const float4*)(rw + (long)d0 * 4);
  float4 r1 = *(const float4*)(rw + (long)(d0 + 1) * 4);
  float4 r2 = *(const float4*)(rw + (long)(d0 + 2) * 4);
  float4 r3 = *(const float4*)(rw + (long)(d0 + 3) * 4);
  float a0 = h0*r0.x + h1*r1.x + h2*r2.x + h3*r3.x;
  float a1 = h0*r0.y + h1*r1.y + h2*r2.y + h3*r3.y;
  float a2 = h0*r0.z + h1*r1.z + h2*r2.z + h3*r3.z;
  float a3 = h0*r0.w + h1*r1.w + h2*r2.w + h3*r3.w;
  #pragma unroll
  for (int off = 32; off; off >>= 1) {
    a0 += __shfl_xor(a0, off); a1 += __shfl_xor(a1, off);
    a2 += __shfl_xor(a2, off); a3 += __shfl_xor(a3, off);
  }
  __shared__ float red2[4][4];
  if (lane == 0){ red2[wv][0] = a0; red2[wv][1] = a1; red2[wv][2] = a2; red2[wv][3] = a3; }
  __syncthreads();
  if (tid == 0) {
    float s0 = red2[0][0] + red2[1][0] + red2[2][0] + red2[3][0];
    float s1 = red2[0][1] + red2[1][1] + red2[2][1] + red2[3][1];
    float s2 = red2[0][2] + red2[1][2] + red2[2][2] + red2[3][2];
    float s3 = red2[0][3] + red2[1][3] + red2[2][3] + red2[3][3];
    float mx = fmaxf(fmaxf(s0, s1), fmaxf(s2, s3));
    float e0 = __expf(s0 - mx), e1 = __expf(s1 - mx);
    float e2 = __expf(s2 - mx), e3 = __expf(s3 - mx);
    float inv = 1.0f / (e0 + e1 + e2 + e3);
    float4 r = {e0 * inv, e1 * inv, e2 * inv, e3 * inv};
    *(float4*)(rout + (long)row * 4) = r;
  }
}

// ---- tier GEMM, 512-thread / 8-wave, 128x128 tile, DBUF 2-phase, BK=32 ------
// C = A(4096x1024) @ Bt(5120x1024)^T, bf16 out, gelu on col<2048.
// BK=32: LDS 32KB -> 4 blocks/CU (32 waves/CU, HW max) vs 2 at BK=64.
// Swizzle: s(row)=(row>>1)&3 over 4 chunks -> 2-way bank conflict (free).
__global__ __launch_bounds__(512) void k_gemm512(
    const unsigned short* __restrict__ A,
    const unsigned short* __restrict__ Bt,
    unsigned short* __restrict__ Cb)
{
  constexpr int BK = 32;
  __shared__ unsigned short As[2][128 * BK];
  __shared__ unsigned short Bs[2][128 * BK];
  // grid (40, 32): T1 XCD chunk + grouped-M (GM=8)
  int lin = blockIdx.y * gridDim.x + blockIdx.x;
  int cols = gridDim.x, rows = gridDim.y;
  int nwg = cols * rows;
  if ((nwg & 7) == 0) lin = (lin & 7) * (nwg >> 3) + (lin >> 3);
  int in_grp = 8 * cols;
  int gid = lin / in_grp;
  int fm = gid * 8;
  int gsz = min(rows - fm, 8);
  int rem = lin - gid * in_grp;
  int pm = fm + (rem % gsz);
  int pn = rem / gsz;
  int bm = pm * 128, bn = pn * 128;

  int tid = threadIdx.x, w = tid >> 6, lane = tid & 63;
  int fr = lane & 15, fg = lane >> 4;
  int wr = (w >> 1) * 32, wc = (w & 1) * 64;   // 8 waves: 4 row-q x 2 col-half

  // staging: wave w covers rows w*16 + (lane>>2); chunk = lane&3 (8 elems).
  // inverse pre-swizzle on global col: chunk ^ ((srow>>1)&3)
  int srow = lane >> 2;
  int schunk = lane & 3;
  int scol = (schunk ^ ((srow >> 1) & 3)) * 8;
  const unsigned short* Ag = A  + (long)(bm + w * 16 + srow) * 1024 + scol;
  const unsigned short* Bg = Bt + (long)(bn + w * 16 + srow) * 1024 + scol;
  int Off = w * 16 * BK;   // wave-uniform LDS element base

  f4v acc[2][4];
  #pragma unroll
  for (int m = 0; m < 2; ++m)
    #pragma unroll
    for (int n = 0; n < 4; ++n)
      acc[m][n] = (f4v){0.f, 0.f, 0.f, 0.f};

  auto stage = [&](int buf, int k0){
    gl16(Ag + k0, &As[buf][Off]);
    gl16(Bg + k0, &Bs[buf][Off]);
  };
  int sw2 = (fr >> 1) & 3;               // read-side XOR (row>>1 == fr>>1 mod 4)
  int kg = (fg ^ sw2) * 8;
  auto compute = [&](int buf){
    s8v af[2], bfv[4];
    #pragma unroll
    for (int m = 0; m < 2; ++m) af[m]  = *(const s8v*)&As[buf][(wr + m * 16 + fr) * BK + kg];
    #pragma unroll
    for (int n = 0; n < 4; ++n) bfv[n] = *(const s8v*)&Bs[buf][(wc + n * 16 + fr) * BK + kg];
    #pragma unroll
    for (int m = 0; m < 2; ++m)
      #pragma unroll
      for (int n = 0; n < 4; ++n)
        acc[m][n] = __builtin_amdgcn_mfma_f32_16x16x32_bf16(af[m], bfv[n], acc[m][n], 0, 0, 0);
  };

  int cur = 0;
  stage(0, 0);
  __syncthreads();
  for (int k0 = 0; k0 < 1024; k0 += BK) {
    if (k0 + BK < 1024) stage(cur ^ 1, k0 + BK);
    compute(cur);
    __syncthreads();
    cur ^= 1;
  }

  int cr = bm + wr + fg * 4, cc = bn + wc + fr;
  #pragma unroll
  for (int m = 0; m < 2; ++m)
    #pragma unroll
    for (int n = 0; n < 4; ++n)
      #pragma unroll
      for (int i = 0; i < 4; ++i) {
        long row = cr + m * 16 + i;
        long col = cc + n * 16;
        float v = acc[m][n][i];
        if (col < 2048) v = gelu_f(v);
        Cb[row * 5120 + col] = f2bf(v);
      }
}

// ---- qkv GEMM (768 blocks) + deferred weight transposes (4608 dual blocks) --
// bid < 768: proven BK=64 512-thr body, out ld 3072, no gelu (cols=24, rows=32).
// bid >= 768: 2x 32x32 fp32->bf16 transpose tiles (tid>>8 halves), covering
// out_w/ew1/wq/wk/wv/ew2/wo (9216 tiles); consumers are >=3 dispatches later.
struct QPack {
  const float *out_w, *ew1, *wq, *wk, *wv, *ew2, *wo;
  unsigned short *w_outt, *w_tiert, *w_ew2t, *w_wot;
};
__global__ __launch_bounds__(512) void k_qkv512(
    const unsigned short* __restrict__ A,
    const unsigned short* __restrict__ Bt,
    unsigned short* __restrict__ Cb, QPack qp)
{
  constexpr int BK = 64;
  __shared__ unsigned short As[2][128 * BK];
  __shared__ unsigned short Bs[2][128 * BK];
  int bid = blockIdx.x;
  int tid = threadIdx.x;

  if (bid >= 768) {
    int sub = tid & 255, half = tid >> 8;
    int g = (bid - 768) * 2 + half;          // [0, 9216)
    const float* in; unsigned short* out; int R, C, bx, base;
    if (g < 1024)      { in = qp.out_w; out = qp.w_outt;                   R = 1024; C = 1024; bx = 32; base = 0; }
    else if (g < 3072) { in = qp.ew1;   out = qp.w_tiert;                  R = 1024; C = 2048; bx = 64; base = 1024; }
    else if (g < 4096) { in = qp.wq;    out = qp.w_tiert + 2048*1024;      R = 1024; C = 1024; bx = 32; base = 3072; }
    else if (g < 5120) { in = qp.wk;    out = qp.w_tiert + 3072*1024;      R = 1024; C = 1024; bx = 32; base = 4096; }
    else if (g < 6144) { in = qp.wv;    out = qp.w_tiert + (size_t)4096*1024; R = 1024; C = 1024; bx = 32; base = 5120; }
    else if (g < 8192) { in = qp.ew2;   out = qp.w_ew2t;                   R = 2048; C = 1024; bx = 32; base = 6144; }
    else               { in = qp.wo;    out = qp.w_wot;                    R = 1024; C = 1024; bx = 32; base = 8192; }
    int rel = g - base;
    int c0 = (rel % bx) * 32, r0 = (rel / bx) * 32;
    int tx = sub & 31, ty = sub >> 5;
    float* T = reinterpret_cast<float*>(&As[0][0]) + half * 1100;  // 32x33 fp32 per half
    #pragma unroll
    for (int i = 0; i < 32; i += 8)
      T[(ty + i) * 33 + tx] = in[(long)(r0 + ty + i) * C + c0 + tx];
    __syncthreads();
    #pragma unroll
    for (int i = 0; i < 32; i += 8)
      out[(long)(c0 + ty + i) * R + r0 + tx] = f2bf(T[tx * 33 + (ty + i)]);
    return;
  }

  // GEMM path: 1-D grid, hardcoded cols=24, rows=32, nwg=768
  int lin = bid;
  lin = (lin & 7) * 96 + (lin >> 3);          // T1 XCD chunk (768/8=96)
  int gid = lin / 192;                         // in_grp = 8*24
  int fm = gid * 8;
  int rem = lin - gid * 192;
  int pm = fm + (rem % 8);                     // gsz = 8 (rows=32)
  int pn = rem / 8;
  int bm = pm * 128, bn = pn * 128;

  int w = tid >> 6, lane = tid & 63;
  int fr = lane & 15, fg = lane >> 4;
  int sw = (fr & 7) * 8;
  int wr = (w >> 1) * 32, wc = (w & 1) * 64;
  int lrow = lane >> 3;
  int lcol = ((lane & 7) ^ lrow) * 8;

  const unsigned short* AgJ[2];
  const unsigned short* BgJ[2];
  int OffJ[2];
  #pragma unroll
  for (int j = 0; j < 2; ++j) {
    AgJ[j] = A  + (long)(bm + j * 64 + w * 8 + lrow) * 1024 + lcol;
    BgJ[j] = Bt + (long)(bn + j * 64 + w * 8 + lrow) * 1024 + lcol;
    OffJ[j] = (j * 64 + w * 8) * BK;
  }

  f4v acc[2][4];
  #pragma unroll
  for (int m = 0; m < 2; ++m)
    #pragma unroll
    for (int n = 0; n < 4; ++n)
      acc[m][n] = (f4v){0.f, 0.f, 0.f, 0.f};

  auto stage = [&](int buf, int k0){
    #pragma unroll
    for (int j = 0; j < 2; ++j) gl16(AgJ[j] + k0, &As[buf][OffJ[j]]);
    #pragma unroll
    for (int j = 0; j < 2; ++j) gl16(BgJ[j] + k0, &Bs[buf][OffJ[j]]);
  };
  auto compute = [&](int buf){
    #pragma unroll
    for (int kk = 0; kk < 2; ++kk) {
      int kg = (kk * 32 + fg * 8) ^ sw;
      s8v af[2], bfv[4];
      #pragma unroll
      for (int m = 0; m < 2; ++m) af[m]  = *(const s8v*)&As[buf][(wr + m * 16 + fr) * BK + kg];
      #pragma unroll
      for (int n = 0; n < 4; ++n) bfv[n] = *(const s8v*)&Bs[buf][(wc + n * 16 + fr) * BK + kg];
      #pragma unroll
      for (int m = 0; m < 2; ++m)
        #pragma unroll
        for (int n = 0; n < 4; ++n)
          acc[m][n] = __builtin_amdgcn_mfma_f32_16x16x32_bf16(af[m], bfv[n], acc[m][n], 0, 0, 0);
    }
  };

  int cur = 0;
  stage(0, 0);
  __syncthreads();
  for (int k0 = 0; k0 < 1024; k0 += BK) {
    if (k0 + BK < 1024) stage(cur ^ 1, k0 + BK);
    compute(cur);
    __syncthreads();
    cur ^= 1;
  }

  int cr = bm + wr + fg * 4, cc = bn + wc + fr;
  #pragma unroll
  for (int m = 0; m < 2; ++m)
    #pragma unroll
    for (int n = 0; n < 4; ++n)
      #pragma unroll
      for (int i = 0; i < 4; ++i) {
        long row = cr + m * 16 + i;
        long col = cc + n * 16;
        Cb[row * 3072 + col] = f2bf(acc[m][n][i]);
      }
}

// ---- qkv split: RoPE + V transpose (bf16 input, r3-proven) ------------------
// grid (T/32, BH), 256 thr. Qb/Kb: [bh][t][64] (Q scaled 1/8). Vt: [bh][64][t].
__global__ __launch_bounds__(256) void k_qkvsplit(const unsigned short* __restrict__ qkv,
    unsigned short* __restrict__ Qb, unsigned short* __restrict__ Kb,
    unsigned short* __restrict__ Vt)
{
  __shared__ unsigned short vt_s[64][40];
  int t0 = blockIdx.x * 32;
  int bh = blockIdx.y;
  int b = bh >> 4, h = bh & 15;
  int tid = threadIdx.x;
  int tl = tid >> 3, jb = (tid & 7) * 4;
  int t = t0 + tl;
  long base = ((long)(b * Tz + t)) * 3072 + h * 64;
  float cs[4], sn[4];
  #pragma unroll
  for (int ii = 0; ii < 4; ++ii) {
    float inv = exp2f(-(float)(jb + ii) * 0.41524101186092030f);
    sincosf((float)t * inv, &sn[ii], &cs[ii]);
  }
  ushort4 q1 = *(const ushort4*)(qkv + base + jb);
  ushort4 q2 = *(const ushort4*)(qkv + base + jb + 32);
  ushort4 k1 = *(const ushort4*)(qkv + base + 1024 + jb);
  ushort4 k2 = *(const ushort4*)(qkv + base + 1024 + jb + 32);
  ushort4 v1 = *(const ushort4*)(qkv + base + 2048 + jb);
  ushort4 v2 = *(const ushort4*)(qkv + base + 2048 + jb + 32);
  float q1a[4] = {bf2f(q1.x), bf2f(q1.y), bf2f(q1.z), bf2f(q1.w)};
  float q2a[4] = {bf2f(q2.x), bf2f(q2.y), bf2f(q2.z), bf2f(q2.w)};
  float k1a[4] = {bf2f(k1.x), bf2f(k1.y), bf2f(k1.z), bf2f(k1.w)};
  float k2a[4] = {bf2f(k2.x), bf2f(k2.y), bf2f(k2.z), bf2f(k2.w)};
  unsigned short va[4] = {v1.x, v1.y, v1.z, v1.w};
  unsigned short vb[4] = {v2.x, v2.y, v2.z, v2.w};
  unsigned short qo1[4], qo2[4], ko1[4], ko2[4];
  #pragma unroll
  for (int ii = 0; ii < 4; ++ii) {
    qo1[ii] = f2bf((q1a[ii] * cs[ii] - q2a[ii] * sn[ii]) * 0.125f);
    qo2[ii] = f2bf((q1a[ii] * sn[ii] + q2a[ii] * cs[ii]) * 0.125f);
    ko1[ii] = f2bf(k1a[ii] * cs[ii] - k2a[ii] * sn[ii]);
    ko2[ii] = f2bf(k1a[ii] * sn[ii] + k2a[ii] * cs[ii]);
    vt_s[jb + ii][tl]      = va[ii];
    vt_s[jb + 32 + ii][tl] = vb[ii];
  }
  long ob = (long)bh * Tz * 64 + (long)t * 64;
  *(ushort4*)(Qb + ob + jb)      = *(ushort4*)qo1;
  *(ushort4*)(Qb + ob + jb + 32) = *(ushort4*)qo2;
  *(ushort4*)(Kb + ob + jb)      = *(ushort4*)ko1;
  *(ushort4*)(Kb + ob + jb + 32) = *(ushort4*)ko2;
  __syncthreads();
  int d = tid >> 2, tc = (tid & 3) * 8;
  *(uint4*)(Vt + (long)bh * 64 * Tz + (long)d * Tz + t0 + tc) = *(const uint4*)&vt_s[d][tc];
}

// ---- merged tail: ew2 split-K (512) + attn2 S lower-tri (144) + V-transpose
// (256) in one dispatch; all three read disjoint tierb columns, outputs
// disjoint, consumers all later in stream.
__global__ __launch_bounds__(512) void k_tail512(
    const unsigned short* __restrict__ tierb,
    const unsigned short* __restrict__ w_ew2t,
    unsigned short* __restrict__ eo, long eoDelta,
    unsigned short* __restrict__ Sb,
    unsigned short* __restrict__ v2t)
{
  constexpr int BK = 64;
  __shared__ unsigned short As[2][128 * BK];
  __shared__ unsigned short Bs[2][128 * BK];
  int bid = blockIdx.x;
  int tid = threadIdx.x;

  if (bid >= 656) {
    // V transpose: in = tierb cols [4096,5120) (ld 5120) -> v2t [d][t] (ld 1024)
    int g0 = (bid - 656) * 16;
    int sub = tid & 255, half = tid >> 8;
    int tx = sub & 31, ty = sub >> 5;
    unsigned short* T = &As[0][0] + half * 1100;   // 32x33 scratch per half
    for (int it = 0; it < 8; ++it) {
      int g = g0 + half * 8 + it;
      int z = g >> 10, rem = g & 1023;
      int r0 = (rem >> 5) * 32, c0 = (rem & 31) * 32;
      const unsigned short* inp = tierb + 4096 + (long)z * ((long)Tz * 5120);
      unsigned short* outp = v2t + (long)z * ((long)Tz * 1024);
      #pragma unroll
      for (int i = 0; i < 32; i += 8)
        T[(ty + i) * 33 + tx] = inp[(long)(r0 + ty + i) * 5120 + c0 + tx];
      __syncthreads();
      #pragma unroll
      for (int i = 0; i < 32; i += 8)
        outp[(long)(c0 + ty + i) * 1024 + r0 + tx] = T[tx * 33 + (ty + i)];
      __syncthreads();
    }
    return;
  }

  int w = tid >> 6, lane = tid & 63;
  int fr = lane & 15, fg = lane >> 4;
  int sw = (fr & 7) * 8;
  int wr = (w >> 1) * 32, wc = (w & 1) * 64;
  int lrow = lane >> 3;
  int lcol = ((lane & 7) ^ lrow) * 8;

  const unsigned short* A;
  const unsigned short* Bt;
  unsigned short* Cout;
  long ldA, ldB;
  int bm, bn;
  float scale;
  if (bid < 512) {
    int z = bid >> 8;
    int lin = bid & 255;
    lin = (lin & 7) * 32 + (lin >> 3);       // T1 swizzle, nwg=256
    int gid = lin / 64;                       // in_grp = 8*cols = 64
    int fm = gid * 8;
    int rem = lin - gid * 64;
    int pm = fm + (rem & 7);                  // gsz = 8 always (rows=32)
    int pn = rem >> 3;
    bm = pm * 128; bn = pn * 128;
    A    = tierb + (long)z * 1024;
    Bt   = w_ew2t + (long)z * 1024;
    Cout = eo + (long)z * eoDelta;
    ldA = 5120; ldB = 2048;
    scale = 1.0f;
  } else {
    int r2 = bid - 512;
    int li = r2 % 36;
    int z  = r2 / 36;
    int r = (int)((sqrtf(8.f * li + 1.f) - 1.f) * 0.5f);
    if ((r + 1) * (r + 2) / 2 <= li) ++r;
    if (r * (r + 1) / 2 > li) --r;
    bm = r * 128; bn = (li - r * (r + 1) / 2) * 128;
    A    = tierb + 2048 + (long)z * ((long)Tz * 5120);
    Bt   = tierb + 3072 + (long)z * ((long)Tz * 5120);
    Cout = Sb + (long)z * ((long)Tz * Tz);
    ldA = 5120; ldB = 5120;
    scale = 0.03125f;
  }

  const unsigned short* AgJ[2];
  const unsigned short* BgJ[2];
  int OffJ[2];
  #pragma unroll
  for (int j = 0; j < 2; ++j) {
    AgJ[j] = A  + (long)(bm + j * 64 + w * 8 + lrow) * ldA + lcol;
    BgJ[j] = Bt + (long)(bn + j * 64 + w * 8 + lrow) * ldB + lcol;
    OffJ[j] = (j * 64 + w * 8) * BK;
  }

  f4v acc[2][4];
  #pragma unroll
  for (int m = 0; m < 2; ++m)
    #pragma unroll
    for (int n = 0; n < 4; ++n)
      acc[m][n] = (f4v){0.f, 0.f, 0.f, 0.f};

  auto stage = [&](int buf, int k0){
    #pragma unroll
    for (int j = 0; j < 2; ++j) gl16(AgJ[j] + k0, &As[buf][OffJ[j]]);
    #pragma unroll
    for (int j = 0; j < 2; ++j) gl16(BgJ[j] + k0, &Bs[buf][OffJ[j]]);
  };
  auto compute = [&](int buf){
    #pragma unroll
    for (int kk = 0; kk < 2; ++kk) {
      int kg = (kk * 32 + fg * 8) ^ sw;
      s8v af[2], bfv[4];
      #pragma unroll
      for (int m = 0; m < 2; ++m) af[m]  = *(const s8v*)&As[buf][(wr + m * 16 + fr) * BK + kg];
      #pragma unroll
      for (int n = 0; n < 4; ++n) bfv[n] = *(const s8v*)&Bs[buf][(wc + n * 16 + fr) * BK + kg];
      #pragma unroll
      for (int m = 0; m < 2; ++m)
        #pragma unroll
        for (int n = 0; n < 4; ++n)
          acc[m][n] = __builtin_amdgcn_mfma_f32_16x16x32_bf16(af[m], bfv[n], acc[m][n], 0, 0, 0);
    }
  };

  int cur = 0;
  stage(0, 0);
  __syncthreads();
  for (int k0 = 0; k0 < 1024; k0 += BK) {
    if (k0 + BK < 1024) stage(cur ^ 1, k0 + BK);
    compute(cur);
    __syncthreads();
    cur ^= 1;
  }

  int cr = bm + wr + fg * 4, cc = bn + wc + fr;
  #pragma unroll
  for (int m = 0; m < 2; ++m)
    #pragma unroll
    for (int n = 0; n < 4; ++n)
      #pragma unroll
      for (int i = 0; i < 4; ++i) {
        long row = cr + m * 16 + i;
        long col = cc + n * 16;
        Cout[row * 1024 + col] = f2bf(acc[m][n][i] * scale);
      }
}

// ---- wo GEMM, 512-thread split-K clone: C(4096x1024), K=1024 -> 2x512 -------
__global__ __launch_bounds__(512) void k_wo512(
    const unsigned short* __restrict__ A,
    const unsigned short* __restrict__ Bt,
    unsigned short* __restrict__ Cb, long sC)
{
  constexpr int BK = 64;
  __shared__ unsigned short As[2][128 * BK];
  __shared__ unsigned short Bs[2][128 * BK];
  A  += (long)blockIdx.z * 512;
  Bt += (long)blockIdx.z * 512;
  Cb += (long)blockIdx.z * sC;
  int lin = blockIdx.y * gridDim.x + blockIdx.x;
  int cols = gridDim.x, rows = gridDim.y;
  int nwg = cols * rows;
  if ((nwg & 7) == 0) lin = (lin & 7) * (nwg >> 3) + (lin >> 3);
  int in_grp = 8 * cols;
  int gid = lin / in_grp;
  int fm = gid * 8;
  int gsz = min(rows - fm, 8);
  int rem = lin - gid * in_grp;
  int pm = fm + (rem % gsz);
  int pn = rem / gsz;
  int bm = pm * 128, bn = pn * 128;

  int tid = threadIdx.x, w = tid >> 6, lane = tid & 63;
  int fr = lane & 15, fg = lane >> 4;
  int sw = (fr & 7) * 8;
  int wr = (w >> 1) * 32, wc = (w & 1) * 64;
  int lrow = lane >> 3;
  int lcol = ((lane & 7) ^ lrow) * 8;

  const unsigned short* AgJ[2];
  const unsigned short* BgJ[2];
  int OffJ[2];
  #pragma unroll
  for (int j = 0; j < 2; ++j) {
    AgJ[j] = A  + (long)(bm + j * 64 + w * 8 + lrow) * 1024 + lcol;
    BgJ[j] = Bt + (long)(bn + j * 64 + w * 8 + lrow) * 1024 + lcol;
    OffJ[j] = (j * 64 + w * 8) * BK;
  }

  f4v acc[2][4];
  #pragma unroll
  for (int m = 0; m < 2; ++m)
    #pragma unroll
    for (int n = 0; n < 4; ++n)
      acc[m][n] = (f4v){0.f, 0.f, 0.f, 0.f};

  auto stage = [&](int buf, int k0){
    #pragma unroll
    for (int j = 0; j < 2; ++j) gl16(AgJ[j] + k0, &As[buf][OffJ[j]]);
    #pragma unroll
    for (int j = 0; j < 2; ++j) gl16(BgJ[j] + k0, &Bs[buf][OffJ[j]]);
  };
  auto compute = [&](int buf){
    #pragma unroll
    for (int kk = 0; kk < 2; ++kk) {
      int kg = (kk * 32 + fg * 8) ^ sw;
      s8v af[2], bfv[4];
      #pragma unroll
      for (int m = 0; m < 2; ++m) af[m]  = *(const s8v*)&As[buf][(wr + m * 16 + fr) * BK + kg];
      #pragma unroll
      for (int n = 0; n < 4; ++n) bfv[n] = *(const s8v*)&Bs[buf][(wc + n * 16 + fr) * BK + kg];
      #pragma unroll
      for (int m = 0; m < 2; ++m)
        #pragma unroll
        for (int n = 0; n < 4; ++n)
          acc[m][n] = __builtin_amdgcn_mfma_f32_16x16x32_bf16(af[m], bfv[n], acc[m][n], 0, 0, 0);
    }
  };

  int cur = 0;
  stage(0, 0);
  __syncthreads();
  for (int k0 = 0; k0 < 512; k0 += BK) {
    if (k0 + BK < 512) stage(cur ^ 1, k0 + BK);
    compute(cur);
    __syncthreads();
    cur ^= 1;
  }

  int cr = bm + wr + fg * 4, cc = bn + wc + fr;
  #pragma unroll
  for (int m = 0; m < 2; ++m)
    #pragma unroll
    for (int n = 0; n < 4; ++n)
      #pragma unroll
      for (int i = 0; i < 4; ++i) {
        long row = cr + m * 16 + i;
        long col = cc + n * 16;
        Cb[row * 1024 + col] = f2bf(acc[m][n][i]);
      }
}

// ---------------- GEMM: C = A(MxK,bf16,lda) @ Bt(NxK,bf16,ldb)^T -------------
// m97 structure + T2 XOR-swizzle + T1 XCD chunk + grouped-M (GM=8) ordering.
// DBUF: 2-phase pipeline. MODE 0: fp32  1: fp32+addsrc  3: bf16
// 6: bf16(v/32)  7: bf16(acc+addsrc).  TRIMAP (BN=64): lower-tri tiles
// c<=2r+1.  TRIK: Keff=bm+128, heavy first.
template<int MODE, int BN, bool TRIMAP, bool TRIK, bool DBUF>
__global__ __launch_bounds__(256) void k_gemm(
    const unsigned short* __restrict__ A,
    const unsigned short* __restrict__ Bt,
    float* __restrict__ Cf, unsigned short* __restrict__ Cb,
    const float* __restrict__ addsrc,
    unsigned short* __restrict__ P1, unsigned short* __restrict__ P2,
    int N, int K, int lda, int ldb,
    long sA, long sB, long sC)
{
  constexpr int BM = 128;
  constexpr int MREP = (BN == 128) ? 4 : 2;
  constexpr int NB = DBUF ? 2 : 1;
  __shared__ unsigned short As[NB][BM * 64];
  __shared__ unsigned short Bs[NB][BN * 64];
  int bm, bn;
  if (TRIMAP) {
    int li = blockIdx.x;
    int nwg = gridDim.x;
    if ((nwg & 7) == 0) li = (li & 7) * (nwg >> 3) + (li >> 3);   // T1
    int r = (int)((sqrtf(4.f * li + 1.f) - 1.f) * 0.5f);
    if ((r + 1) * (r + 2) <= li) ++r;
    if (r * (r + 1) > li) --r;
    bm = r * 128; bn = (li - r * (r + 1)) * BN;
  } else {
    int lin = blockIdx.y * gridDim.x + blockIdx.x;
    int nwg = gridDim.x * gridDim.y;
    if ((nwg & 7) == 0) lin = (lin & 7) * (nwg >> 3) + (lin >> 3); // T1 XCD chunk
    int cols = gridDim.x, rows = gridDim.y;
    constexpr int GM = 8;
    int in_grp = GM * cols;
    int gid = lin / in_grp;
    int fm = gid * GM;
    int gsz = min(rows - fm, GM);
    int rem = lin - gid * in_grp;
    int pm = fm + (rem % gsz);
    int pn = rem / gsz;
    if (TRIK) pm = rows - 1 - pm;     // heavy (large Keff) first
    bm = pm * BM; bn = pn * BN;
  }
  A  += (long)blockIdx.z * sA;
  Bt += (long)blockIdx.z * sB;
  int tid = threadIdx.x, w = tid >> 6, lane = tid & 63;
  int wr, wc;
  if (BN == 128) { wr = (w >> 1) * 64; wc = (w & 1) * 64; }
  else           { wr = w * 32;        wc = 0; }
  f4v acc[MREP][4];
  #pragma unroll
  for (int m = 0; m < MREP; ++m)
    #pragma unroll
    for (int n = 0; n < 4; ++n)
      acc[m][n] = (f4v){0.f, 0.f, 0.f, 0.f};

  int Keff = K;
  if (TRIK) Keff = min(K, bm + BM);

  int lrow = lane >> 3;
  int lcol = (((lane & 7) ^ lrow) * 8);
  const unsigned short* AgJ[4];
  int AsOff[4];
  #pragma unroll
  for (int j = 0; j < 4; ++j) {
    AgJ[j] = A + (long)(bm + w * 32 + j * 8 + lrow) * lda + lcol;
    AsOff[j] = (w * 32 + j * 8) * 64;
  }
  constexpr int BCH = BN / 8 / 4;
  const unsigned short* BgJ[BCH];
  int BsOff[BCH];
  #pragma unroll
  for (int j = 0; j < BCH; ++j) {
    BgJ[j] = Bt + (long)(bn + w * (BCH * 8) + j * 8 + lrow) * ldb + lcol;
    BsOff[j] = (w * (BCH * 8) + j * 8) * 64;
  }

  int fr = lane & 15, fg = lane >> 4;
  int sw = (fr & 7) * 8;

  auto stage = [&](int buf, int k0){
    #pragma unroll
    for (int j = 0; j < 4; ++j) gl16(AgJ[j] + k0, &As[buf][AsOff[j]]);
    #pragma unroll
    for (int j = 0; j < BCH; ++j) gl16(BgJ[j] + k0, &Bs[buf][BsOff[j]]);
  };
  auto compute = [&](int buf){
    #pragma unroll
    for (int kk = 0; kk < 2; ++kk) {
      int kg = (kk * 32 + fg * 8) ^ sw;
      s8v af[MREP], bfv[4];
      #pragma unroll
      for (int m = 0; m < MREP; ++m) af[m]  = *(const s8v*)&As[buf][(wr + m * 16 + fr) * 64 + kg];
      #pragma unroll
      for (int n = 0; n < 4; ++n)    bfv[n] = *(const s8v*)&Bs[buf][(wc + n * 16 + fr) * 64 + kg];
      #pragma unroll
      for (int m = 0; m < MREP; ++m)
        #pragma unroll
        for (int n = 0; n < 4; ++n)
          acc[m][n] = __builtin_amdgcn_mfma_f32_16x16x32_bf16(af[m], bfv[n], acc[m][n], 0, 0, 0);
    }
  };

  if (DBUF) {
    int cur = 0;
    stage(0, 0);
    __syncthreads();
    for (int k0 = 0; k0 < Keff; k0 += 64) {
      if (k0 + 64 < Keff) stage(cur ^ 1, k0 + 64);
      compute(cur);
      __syncthreads();
      cur ^= 1;
    }
  } else {
    for (int k0 = 0; k0 < Keff; k0 += 64) {
      __syncthreads();
      stage(0, k0);
      __syncthreads();
      compute(0);
    }
  }

  int cr0 = bm + wr + fg * 4;
  int cc0 = bn + wc + fr;

  #pragma unroll
  for (int m = 0; m < MREP; ++m)
    #pragma unroll
    for (int n = 0; n < 4; ++n)
      #pragma unroll
      for (int i = 0; i < 4; ++i) {
        long row = cr0 + m * 16 + i, col = cc0 + n * 16;
        long idx = (long)blockIdx.z * sC + row * (long)N + col;
        float v = acc[m][n][i];
        if (MODE == 1 || MODE == 7) v += addsrc[idx];
        if (MODE == 6) v *= 0.03125f;
        if (MODE <= 1) Cf[idx] = v; else Cb[idx] = f2bf(v);
      }
}

// ---------------- backbone flash attention, MFMA (hd=64) ---------------------
// heavy-first dispatch + reg-staged K/V prefetch (issue-early / write-late).
__global__ __launch_bounds__(256) void k_attn_mfma(
    const unsigned short* __restrict__ Qb, const unsigned short* __restrict__ Kb,
    const unsigned short* __restrict__ Vt, unsigned short* __restrict__ ao)
{
  __shared__ unsigned short Ks[64][72];
  __shared__ unsigned short Vs[64][72];   // Vs[d][key]
  __shared__ unsigned short Ps[4][16][72];
  int qb = 15 - (blockIdx.x >> 6);
  int bh = blockIdx.x & 63;
  int b = bh >> 4, h = bh & 15;
  int t0 = qb * 64;
  int tid = threadIdx.x, w = tid >> 6, lane = tid & 63;
  int fr = lane & 15, fg = lane >> 4;

  const unsigned short* qp = Qb + (long)bh * Tz * 64 + (long)(t0 + w * 16 + fr) * 64 + fg * 8;
  s8v qf[2] = { *(const s8v*)qp, *(const s8v*)(qp + 32) };

  f4v o_acc[4];
  #pragma unroll
  for (int n = 0; n < 4; ++n) o_acc[n] = (f4v){0.f, 0.f, 0.f, 0.f};
  float m_[4] = {-1e30f, -1e30f, -1e30f, -1e30f};
  float l_[4] = {0.f, 0.f, 0.f, 0.f};

  int sr = tid >> 3, sc = (tid & 7) * 8;
  const unsigned short* Kg = Kb + (long)bh * Tz * 64 + (long)sr * 64 + sc;
  const unsigned short* Vg = Vt + (long)bh * 64 * Tz + (long)sr * Tz + sc;

  uint4 pk0, pk1, pv0, pv1;
  auto loadregs = [&](int k0){
    pk0 = *(const uint4*)(Kg + (long)k0 * 64);
    pk1 = *(const uint4*)(Kg + (long)(k0 + 32) * 64);
    pv0 = *(const uint4*)(Vg + k0);
    pv1 = *(const uint4*)(Vg + (long)32 * Tz + k0);
  };
  auto storelds = [&](){
    *(uint4*)&Ks[sr][sc]      = pk0;
    *(uint4*)&Ks[sr + 32][sc] = pk1;
    *(uint4*)&Vs[sr][sc]      = pv0;
    *(uint4*)&Vs[sr + 32][sc] = pv1;
  };

  loadregs(0);
  storelds();
  __syncthreads();

  for (int kt = 0; kt <= qb; ++kt) {
    int k0 = kt * 64;
    if (kt < qb) loadregs(k0 + 64);   // issue next tile's loads early

    f4v sacc[4];
    #pragma unroll
    for (int n = 0; n < 4; ++n) sacc[n] = (f4v){0.f, 0.f, 0.f, 0.f};
    #pragma unroll
    for (int kk = 0; kk < 2; ++kk) {
      int kg = kk * 32 + fg * 8;
      #pragma unroll
      for (int n = 0; n < 4; ++n) {
        s8v bf = *(const s8v*)&Ks[n * 16 + fr][kg];
        sacc[n] = __builtin_amdgcn_mfma_f32_16x16x32_bf16(qf[kk], bf, sacc[n], 0, 0, 0);
      }
    }

    bool full = (kt < qb);
    float p[4][4], alpha[4];
    #pragma unroll
    for (int i = 0; i < 4; ++i) {
      int trow = t0 + w * 16 + fg * 4 + i;
      float mx = -1e30f;
      #pragma unroll
      for (int n = 0; n < 4; ++n) {
        float sval = sacc[n][i];
        if (!full) {
          int key = k0 + n * 16 + fr;
          sval = (key <= trow) ? sval : -1e30f;
        }
        p[n][i] = sval;
        mx = fmaxf(mx, sval);
      }
      mx = fmaxf(mx, __shfl_xor(mx, 1));
      mx = fmaxf(mx, __shfl_xor(mx, 2));
      mx = fmaxf(mx, __shfl_xor(mx, 4));
      mx = fmaxf(mx, __shfl_xor(mx, 8));
      float mnew = fmaxf(m_[i], mx);
      alpha[i] = __expf(m_[i] - mnew);
      m_[i] = mnew;
      float ps = 0.f;
      #pragma unroll
      for (int n = 0; n < 4; ++n) {
        float pv = __expf(p[n][i] - mnew);
        p[n][i] = pv;
        ps += pv;
      }
      ps += __shfl_xor(ps, 1); ps += __shfl_xor(ps, 2);
      ps += __shfl_xor(ps, 4); ps += __shfl_xor(ps, 8);
      l_[i] = l_[i] * alpha[i] + ps;
    }
    #pragma unroll
    for (int n = 0; n < 4; ++n)
      #pragma unroll
      for (int i = 0; i < 4; ++i)
        o_acc[n][i] *= alpha[i];
    #pragma unroll
    for (int n = 0; n < 4; ++n)
      #pragma unroll
      for (int i = 0; i < 4; ++i)
        Ps[w][fg * 4 + i][n * 16 + fr] = f2bf(p[n][i]);

    #pragma unroll
    for (int kk = 0; kk < 2; ++kk) {
      int kg = kk * 32 + fg * 8;
      s8v pa = *(const s8v*)&Ps[w][fr][kg];
      #pragma unroll
      for (int n = 0; n < 4; ++n) {
        s8v vb = *(const s8v*)&Vs[n * 16 + fr][kg];
        o_acc[n] = __builtin_amdgcn_mfma_f32_16x16x32_bf16(pa, vb, o_acc[n], 0, 0, 0);
      }
    }

    if (kt < qb) {
      __syncthreads();   // all waves done reading Ks/Vs
      storelds();        // write prefetched tile (single LDS buffer)
      __syncthreads();   // writes visible
    }
  }

  float inv[4];
  #pragma unroll
  for (int i = 0; i < 4; ++i) inv[i] = 1.0f / l_[i];
  #pragma unroll
  for (int n = 0; n < 4; ++n)
    #pragma unroll
    for (int i = 0; i < 4; ++i) {
      int t = t0 + w * 16 + fg * 4 + i;
      ao[((long)(b * Tz + t)) * Dz + h * 64 + n * 16 + fr] = f2bf(o_acc[n][i] * inv[i]);
    }
}

// ---------------- causal softmax (attn2): S bf16 -> P bf16 -------------------
__global__ __launch_bounds__(256) void k_softmax_causal(const unsigned short* __restrict__ S,
    unsigned short* __restrict__ P)
{
  long row = blockIdx.x;
  int t = (int)(row & (Tz - 1));
  int tid = threadIdx.x;
  const unsigned short* sp = S + row * Tz;
  ushort4 v = ((const ushort4*)sp)[tid];
  float vv[4];
  vv[0] = (tid*4 + 0 <= t) ? bf2f(v.x) : -1e30f;
  vv[1] = (tid*4 + 1 <= t) ? bf2f(v.y) : -1e30f;
  vv[2] = (tid*4 + 2 <= t) ? bf2f(v.z) : -1e30f;
  vv[3] = (tid*4 + 3 <= t) ? bf2f(v.w) : -1e30f;
  float mx = fmaxf(fmaxf(vv[0], vv[1]), fmaxf(vv[2], vv[3]));
  int lane = tid & 63, wv = tid >> 6;
  #pragma unroll
  for (int off = 32; off; off >>= 1) mx = fmaxf(mx, __shfl_xor(mx, off));
  __shared__ float red[8];
  if (lane == 0) red[wv] = mx;
  __syncthreads();
  mx = fmaxf(fmaxf(red[0], red[1]), fmaxf(red[2], red[3]));
  float p[4];
  float s = 0.f;
  #pragma unroll
  for (int i = 0; i < 4; ++i){ p[i] = __expf(vv[i] - mx); s += p[i]; }
  #pragma unroll
  for (int off = 32; off; off >>= 1) s += __shfl_xor(s, off);
  if (lane == 0) red[4 + wv] = s;
  __syncthreads();
  s = red[4] + red[5] + red[6] + red[7];
  float inv = 1.0f / s;
  ushort4 ov;
  ov.x = f2bf(p[0] * inv); ov.y = f2bf(p[1] * inv);
  ov.z = f2bf(p[2] * inv); ov.w = f2bf(p[3] * inv);
  *((ushort4*)(P + row * Tz) + tid) = ov;
}

// ---------------- fused conv tier + combine + sink scale ---------------------
__global__ __launch_bounds__(256) void k_combine(
    const unsigned short* __restrict__ x2, const unsigned short* __restrict__ hbf,
    const unsigned short* __restrict__ eoa, const unsigned short* __restrict__ eob,
    const unsigned short* __restrict__ ap, const unsigned short* __restrict__ ap2,
    const float* __restrict__ rout, const float* __restrict__ convw,
    const float* __restrict__ tg, const float* __restrict__ sinkp,
    float* __restrict__ outx)
{
  int row = blockIdx.x, tid = threadIdx.x;
  int t = row & (Tz - 1), b = row >> 10;
  int d0 = tid * 4;
  ushort4 xu = *(const ushort4*)(x2 + (long)row * Dz + d0);
  ushort4 ea = *(const ushort4*)(eoa + (long)row * Dz + d0);
  ushort4 eb = *(const ushort4*)(eob + (long)row * Dz + d0);
  ushort4 a4 = *(const ushort4*)(ap + (long)row * Dz + d0);
  ushort4 a42 = *(const ushort4*)(ap2 + (long)row * Dz + d0);
  float4 t4 = *(const float4*)(tg + d0);
  float4 r4 = *(const float4*)(rout + (long)row * 4);
  float sks = fabsf(sinkp[0]);
  float kv = 1.0f - r4.w * (1.0f - sks);
  const float4* cwp = (const float4*)(convw + (long)d0 * 3);
  float4 c0 = cwp[0], c1 = cwp[1], c2 = cwp[2];
  float cwf[12] = {c0.x, c0.y, c0.z, c0.w, c1.x, c1.y, c1.z, c1.w, c2.x, c2.y, c2.z, c2.w};
  float hv[3][4];
  #pragma unroll
  for (int tap = 0; tap < 3; ++tap) {
    int tt = t - 2 + tap;
    if (tt >= 0) {
      ushort4 hu = *((const ushort4*)(hbf + ((long)(b * Tz + tt)) * Dz + d0));
      hv[tap][0] = bf2f(hu.x); hv[tap][1] = bf2f(hu.y);
      hv[tap][2] = bf2f(hu.z); hv[tap][3] = bf2f(hu.w);
    } else {
      hv[tap][0] = 0.f; hv[tap][1] = 0.f; hv[tap][2] = 0.f; hv[tap][3] = 0.f;
    }
  }
  float ov[4];
  float xi[4] = {bf2f(xu.x), bf2f(xu.y), bf2f(xu.z), bf2f(xu.w)};
  float ei[4] = {bf2f(ea.x) + bf2f(eb.x), bf2f(ea.y) + bf2f(eb.y),
                 bf2f(ea.z) + bf2f(eb.z), bf2f(ea.w) + bf2f(eb.w)};
  float ai[4] = {bf2f(a4.x) + bf2f(a42.x), bf2f(a4.y) + bf2f(a42.y),
                 bf2f(a4.z) + bf2f(a42.z), bf2f(a4.w) + bf2f(a42.w)};
  float ti[4] = {t4.x, t4.y, t4.z, t4.w};
  #pragma unroll
  for (int i = 0; i < 4; ++i) {
    float conv = hv[0][i] * cwf[i*3 + 0] + hv[1][i] * cwf[i*3 + 1] + hv[2][i] * cwf[i*3 + 2];
    float comb = gelu_f(conv) * r4.x + ei[i] * r4.y + ai[i] * r4.z;
    ov[i] = (xi[i] + comb * ti[i]) * kv;
  }
  float4 res = {ov[0], ov[1], ov[2], ov[3]};
  *(float4*)(outx + (long)row * Dz + d0) = res;
}

// ---------------- host launcher ----------------------------------------------
extern "C" void kernel_launch(void* const* d_in, const int* in_sizes, int n_in,
                              void* d_out, int out_size, void* d_ws, size_t ws_size,
                              hipStream_t stream) {
  (void)in_sizes; (void)n_in; (void)out_size; (void)ws_size;
  const float* x       = (const float*)d_in[0];
  const float* ln1_w   = (const float*)d_in[1];
  const float* ln1_b   = (const float*)d_in[2];
  const float* qkv_w   = (const float*)d_in[3];
  const float* out_w   = (const float*)d_in[4];
  const float* ln2_w   = (const float*)d_in[5];
  const float* ln2_b   = (const float*)d_in[6];
  const float* router_w= (const float*)d_in[7];
  const float* conv_w  = (const float*)d_in[8];
  const float* ew1     = (const float*)d_in[9];
  const float* ew2     = (const float*)d_in[10];
  const float* at_wq   = (const float*)d_in[11];
  const float* at_wk   = (const float*)d_in[12];
  const float* at_wv   = (const float*)d_in[13];
  const float* at_wo   = (const float*)d_in[14];
  const float* tg      = (const float*)d_in[15];
  const float* sinkp   = (const float*)d_in[16];
  float* outx = (float*)d_out;
  float* rout = outx + (size_t)NTz * Dz;

  char* ws = (char*)d_ws;
  size_t off = 0;
  auto alloc = [&](size_t bytes) -> char* {
    char* p = ws + off;
    off += (bytes + 255) & ~(size_t)255;
    return p;
  };
  const long TD = (long)Tz * Dz, TT = (long)Tz * Tz;

  // ws budget: <= proven 159.4 MB (total ~151 MB).
  unsigned short* w_qkvt  = (unsigned short*)alloc((size_t)3072*1024*2);
  unsigned short* w_outt  = (unsigned short*)alloc((size_t)1024*1024*2);
  unsigned short* w_tiert = (unsigned short*)alloc((size_t)5120*1024*2); // [ew1|wq|wk|wv]^T
  unsigned short* w_ew2t  = (unsigned short*)alloc((size_t)1024*2048*2);
  unsigned short* w_wot   = (unsigned short*)alloc((size_t)1024*1024*2);
  unsigned short* h1bf    = (unsigned short*)alloc((size_t)NTz*Dz*2);
  unsigned short* tierb   = (unsigned short*)alloc((size_t)NTz*5120*2);  // 40 MB
  unsigned short* aobf    = (unsigned short*)alloc((size_t)NTz*Dz*2);
  unsigned short* x2b     = (unsigned short*)alloc((size_t)NTz*Dz*2);    // bf16 residual
  unsigned short* hbf     = (unsigned short*)alloc((size_t)NTz*Dz*2);
  unsigned short* Pbf     = (unsigned short*)alloc((size_t)Bz*Tz*Tz*2);
  unsigned short* v2tbf   = (unsigned short*)alloc((size_t)NTz*Dz*2);
  unsigned short* a2obf   = (unsigned short*)alloc((size_t)NTz*Dz*2);
  unsigned short* eofb    = (unsigned short*)alloc((size_t)NTz*Dz*2);    // split-K half 0
  unsigned short* a2pb    = (unsigned short*)alloc((size_t)NTz*Dz*2);
  unsigned short* Sbf     = (unsigned short*)alloc((size_t)Bz*Tz*Tz*2);  // 8 MB

  // aliases (lifetime-disjoint):
  unsigned short* qkvb = tierb;               // qkv bf16 [row][3072]; dead after
                                              // qkvsplit; tierb written later
  unsigned short* Qb = x2b;                   // x2b written by out-proj (after attn)
  unsigned short* Kb = Pbf;                   // Pbf written by softmax (after attn)
  unsigned short* Vt = a2pb;                  // a2pb written by wo GEMM (after attn)
  unsigned short* eofb2 = h1bf;               // h1bf dead after qkv GEMM; split-K half 1
  long eoDelta = (long)(eofb2 - eofb);        // z*sC lands z=1 in eofb2
  unsigned short* a2pb2 = Sbf;                // Sbf dead after softmax; wo half 1
  long woDelta = (long)(a2pb2 - a2pb);        // z*sC lands z=1 in Sbf

  dim3 blk(256);

  // head: qkv_w transpose (critical path) + LN1, one dispatch
  k_head<<<dim3(7168), blk, 0, stream>>>(qkv_w, w_qkvt, x, ln1_w, ln1_b, h1bf);

  // qkv GEMM (768 blocks) + deferred weight transposes (4608 blocks)
  QPack qp = {out_w, ew1, at_wq, at_wk, at_wv, ew2, at_wo,
              w_outt, w_tiert, w_ew2t, w_wot};
  k_qkv512<<<dim3(5376), dim3(512), 0, stream>>>(h1bf, w_qkvt, qkvb, qp);
  k_qkvsplit<<<dim3(32, 64), blk, 0, stream>>>(qkvb, Qb, Kb, Vt);
  k_attn_mfma<<<dim3(1024), blk, 0, stream>>>(Qb, Kb, Vt, aobf);
  k_gemm<7,64,false,false,true><<<dim3(16, 32), blk, 0, stream>>>(aobf, w_outt, nullptr,
      x2b, x, nullptr, nullptr, 1024, 1024, 1024, 1024, 0, 0, 0);
  // tiers
  k_ln_router<<<NTz, blk, 0, stream>>>(x2b, ln2_w, ln2_b, router_w, hbf, rout);
  // tier GEMM: BK=32 variant, 4 blocks/CU (32 waves/CU)
  k_gemm512<<<dim3(40, 32), dim3(512), 0, stream>>>(hbf, w_tiert, tierb);
  // merged tail: ew2 split-K (512) + attn2 S (144) + V2 transpose (256)
  k_tail512<<<dim3(912), dim3(512), 0, stream>>>(tierb, w_ew2t, eofb, eoDelta,
      Sbf, v2tbf);
  k_softmax_causal<<<NTz, blk, 0, stream>>>(Sbf, Pbf);
  k_gemm<3,64,false,true,true><<<dim3(16, 8, 4), blk, 0, stream>>>(Pbf, v2tbf, nullptr,
      a2obf, nullptr, nullptr, nullptr, 1024, 1024, 1024, 1024, TT, TD, TD);
  // wo split-K (512-thr): z=0 -> a2pb, z=1 -> a2pb + woDelta (= Sbf)
  k_wo512<<<dim3(8, 32, 2), dim3(512), 0, stream>>>(a2obf, w_wot, a2pb, woDelta);
  k_combine<<<NTz, blk, 0, stream>>>(x2b, hbf, eofb, eofb2, a2pb, a2pb2, rout,
      conv_w, tg, sinkp, outx);
}

// Round 24
// 259.573 us; speedup vs baseline: 1.0165x; 1.0165x over previous
//
#include <hip/hip_runtime.h>

#define Bz 4
#define Tz 1024
#define Dz 1024
#define Hz 16
#define NTz (Bz*Tz)

typedef short s8v __attribute__((ext_vector_type(8)));
typedef float f4v __attribute__((ext_vector_type(4)));

__device__ __forceinline__ float bf2f(unsigned short u){
  unsigned int x = ((unsigned int)u) << 16;
  return __builtin_bit_cast(float, x);
}
__device__ __forceinline__ unsigned short f2bf(float f){
  unsigned int x = __builtin_bit_cast(unsigned int, f);
  x += 0x7fffu + ((x >> 16) & 1u);
  return (unsigned short)(x >> 16);
}
// gelu tanh-approx == x * sigmoid(1.5957691216f*(x + 0.044715f*x^3))
__device__ __forceinline__ float gelu_f(float x){
  float z = 1.5957691216057308f * (x + 0.044715f * x * x * x);
  return x / (1.0f + __expf(-z));
}
// async global->LDS, 16B per lane; lds base must be wave-uniform
__device__ __forceinline__ void gl16(const unsigned short* g, unsigned short* l){
  __builtin_amdgcn_global_load_lds(
      (const __attribute__((address_space(1))) unsigned int*)g,
      (__attribute__((address_space(3))) unsigned int*)l, 16, 0, 0);
}

// ---- head: qkv_w transpose (3072 blocks) + LN1 (4096 blocks), independent ---
__global__ __launch_bounds__(256) void k_head(const float* __restrict__ qkv_w,
    unsigned short* __restrict__ w_qkvt, const float* __restrict__ x,
    const float* __restrict__ ln1_w, const float* __restrict__ ln1_b,
    unsigned short* __restrict__ h1bf)
{
  __shared__ float tile[32][33];
  __shared__ float red[8];
  int bid = blockIdx.x, tid = threadIdx.x;
  if (bid < 3072) {
    int c0 = (bid % 96) * 32, r0 = (bid / 96) * 32;
    int tx = tid & 31, ty = tid >> 5;
    #pragma unroll
    for (int i = 0; i < 32; i += 8)
      tile[ty + i][tx] = qkv_w[(long)(r0 + ty + i) * 3072 + c0 + tx];
    __syncthreads();
    #pragma unroll
    for (int i = 0; i < 32; i += 8)
      w_qkvt[(long)(c0 + ty + i) * 1024 + r0 + tx] = f2bf(tile[tx][ty + i]);
    return;
  }
  int row = bid - 3072;
  const float4* xp = (const float4*)(x + (long)row * Dz);
  float4 v = xp[tid];
  float s  = v.x + v.y + v.z + v.w;
  float ss = v.x*v.x + v.y*v.y + v.z*v.z + v.w*v.w;
  int lane = tid & 63, wv = tid >> 6;
  #pragma unroll
  for (int off = 32; off; off >>= 1){ s += __shfl_xor(s, off); ss += __shfl_xor(ss, off); }
  if (lane == 0){ red[wv] = s; red[4 + wv] = ss; }
  __syncthreads();
  s  = red[0] + red[1] + red[2] + red[3];
  ss = red[4] + red[5] + red[6] + red[7];
  float mean = s * (1.0f / Dz);
  float var  = ss * (1.0f / Dz) - mean * mean;
  float rstd = rsqrtf(var + 1e-5f);
  float4 wg = ((const float4*)ln1_w)[tid];
  float4 bg = ((const float4*)ln1_b)[tid];
  ushort4 ov;
  ov.x = f2bf((v.x - mean) * rstd * wg.x + bg.x);
  ov.y = f2bf((v.y - mean) * rstd * wg.y + bg.y);
  ov.z = f2bf((v.z - mean) * rstd * wg.z + bg.z);
  ov.w = f2bf((v.w - mean) * rstd * wg.w + bg.w);
  *((ushort4*)(h1bf + (long)row * Dz) + tid) = ov;
}

// ---- layernorm + router fused: bf16 x2 in -> bf16 h, fp32 softmax4 ----------
__global__ __launch_bounds__(256) void k_ln_router(const unsigned short* __restrict__ x2,
    const float* __restrict__ w, const float* __restrict__ b,
    const float* __restrict__ rw, unsigned short* __restrict__ out,
    float* __restrict__ rout)
{
  int row = blockIdx.x, tid = threadIdx.x;
  ushort4 xu = *((const ushort4*)(x2 + (long)row * Dz) + tid);
  float4 v = {bf2f(xu.x), bf2f(xu.y), bf2f(xu.z), bf2f(xu.w)};
  float s  = v.x + v.y + v.z + v.w;
  float ss = v.x*v.x + v.y*v.y + v.z*v.z + v.w*v.w;
  int lane = tid & 63, wv = tid >> 6;
  #pragma unroll
  for (int off = 32; off; off >>= 1){ s += __shfl_xor(s, off); ss += __shfl_xor(ss, off); }
  __shared__ float red[8];
  if (lane == 0){ red[wv] = s; red[4 + wv] = ss; }
  __syncthreads();
  s  = red[0] + red[1] + red[2] + red[3];
  ss = red[4] + red[5] + red[6] + red[7];
  float mean = s * (1.0f / Dz);
  float var  = ss * (1.0f / Dz) - mean * mean;
  float rstd = rsqrtf(var + 1e-5f);
  float4 wg = ((const float4*)w)[tid];
  float4 bg = ((const float4*)b)[tid];
  float h0 = (v.x - mean) * rstd * wg.x + bg.x;
  float h1 = (v.y - mean) * rstd * wg.y + bg.y;
  float h2 = (v.z - mean) * rstd * wg.z + bg.z;
  float h3 = (v.w - mean) * rstd * wg.w + bg.w;
  ushort4 ov;
  ov.x = f2bf(h0); ov.y = f2bf(h1); ov.z = f2bf(h2); ov.w = f2bf(h3);
  *((ushort4*)(out + (long)row * Dz) + tid) = ov;
  // router dot-products
  int d0 = tid * 4;
  float4 r0 = *(const float4*)(rw + (long)d0 * 4);
  float4 r1 = *(const float4*)(rw + (long)(d0 + 1) * 4);
  float4 r2 = *(const float4*)(rw + (long)(d0 + 2) * 4);
  float4 r3 = *(const float4*)(rw + (long)(d0 + 3) * 4);
  float a0 = h0*r0.x + h1*r1.x + h2*r2.x + h3*r3.x;
  float a1 = h0*r0.y + h1*r1.y + h2*r2.y + h3*r3.y;
  float a2 = h0*r0.z + h1*r1.z + h2*r2.z + h3*r3.z;
  float a3 = h0*r0.w + h1*r1.w + h2*r2.w + h3*r3.w;
  #pragma unroll
  for (int off = 32; off; off >>= 1) {
    a0 += __shfl_xor(a0, off); a1 += __shfl_xor(a1, off);
    a2 += __shfl_xor(a2, off); a3 += __shfl_xor(a3, off);
  }
  __shared__ float red2[4][4];
  if (lane == 0){ red2[wv][0] = a0; red2[wv][1] = a1; red2[wv][2] = a2; red2[wv][3] = a3; }
  __syncthreads();
  if (tid == 0) {
    float s0 = red2[0][0] + red2[1][0] + red2[2][0] + red2[3][0];
    float s1 = red2[0][1] + red2[1][1] + red2[2][1] + red2[3][1];
    float s2 = red2[0][2] + red2[1][2] + red2[2][2] + red2[3][2];
    float s3 = red2[0][3] + red2[1][3] + red2[2][3] + red2[3][3];
    float mx = fmaxf(fmaxf(s0, s1), fmaxf(s2, s3));
    float e0 = __expf(s0 - mx), e1 = __expf(s1 - mx);
    float e2 = __expf(s2 - mx), e3 = __expf(s3 - mx);
    float inv = 1.0f / (e0 + e1 + e2 + e3);
    float4 r = {e0 * inv, e1 * inv, e2 * inv, e3 * inv};
    *(float4*)(rout + (long)row * 4) = r;
  }
}

// ---- tier GEMM, 512-thread / 8-wave, 128x128 tile, DBUF 2-phase -------------
// C = A(4096x1024) @ Bt(5120x1024)^T, bf16 out, gelu on col<2048.
// BK=64 proven config (r23 A/B: BK=32 doubled occupancy to 52% but MfmaUtil
// flat at 24% -> structure-bound, not occupancy-bound; BK=64 retained).
__global__ __launch_bounds__(512) void k_gemm512(
    const unsigned short* __restrict__ A,
    const unsigned short* __restrict__ Bt,
    unsigned short* __restrict__ Cb)
{
  constexpr int BK = 64;
  __shared__ unsigned short As[2][128 * BK];
  __shared__ unsigned short Bs[2][128 * BK];
  // grid (40, 32): T1 XCD chunk + grouped-M (GM=8)
  int lin = blockIdx.y * gridDim.x + blockIdx.x;
  int cols = gridDim.x, rows = gridDim.y;
  int nwg = cols * rows;
  if ((nwg & 7) == 0) lin = (lin & 7) * (nwg >> 3) + (lin >> 3);
  int in_grp = 8 * cols;
  int gid = lin / in_grp;
  int fm = gid * 8;
  int gsz = min(rows - fm, 8);
  int rem = lin - gid * in_grp;
  int pm = fm + (rem % gsz);
  int pn = rem / gsz;
  int bm = pm * 128, bn = pn * 128;

  int tid = threadIdx.x, w = tid >> 6, lane = tid & 63;
  int fr = lane & 15, fg = lane >> 4;
  int sw = (fr & 7) * 8;
  int wr = (w >> 1) * 32, wc = (w & 1) * 64;   // 8 waves: 4 row-q x 2 col-half
  int lrow = lane >> 3;
  int lcol = ((lane & 7) ^ lrow) * 8;          // T2 inverse pre-swizzle

  const unsigned short* AgJ[2];
  const unsigned short* BgJ[2];
  int OffJ[2];
  #pragma unroll
  for (int j = 0; j < 2; ++j) {
    AgJ[j] = A  + (long)(bm + j * 64 + w * 8 + lrow) * 1024 + lcol;
    BgJ[j] = Bt + (long)(bn + j * 64 + w * 8 + lrow) * 1024 + lcol;
    OffJ[j] = (j * 64 + w * 8) * BK;
  }

  f4v acc[2][4];
  #pragma unroll
  for (int m = 0; m < 2; ++m)
    #pragma unroll
    for (int n = 0; n < 4; ++n)
      acc[m][n] = (f4v){0.f, 0.f, 0.f, 0.f};

  auto stage = [&](int buf, int k0){
    #pragma unroll
    for (int j = 0; j < 2; ++j) gl16(AgJ[j] + k0, &As[buf][OffJ[j]]);
    #pragma unroll
    for (int j = 0; j < 2; ++j) gl16(BgJ[j] + k0, &Bs[buf][OffJ[j]]);
  };
  auto compute = [&](int buf){
    #pragma unroll
    for (int kk = 0; kk < 2; ++kk) {
      int kg = (kk * 32 + fg * 8) ^ sw;
      s8v af[2], bfv[4];
      #pragma unroll
      for (int m = 0; m < 2; ++m) af[m]  = *(const s8v*)&As[buf][(wr + m * 16 + fr) * BK + kg];
      #pragma unroll
      for (int n = 0; n < 4; ++n) bfv[n] = *(const s8v*)&Bs[buf][(wc + n * 16 + fr) * BK + kg];
      #pragma unroll
      for (int m = 0; m < 2; ++m)
        #pragma unroll
        for (int n = 0; n < 4; ++n)
          acc[m][n] = __builtin_amdgcn_mfma_f32_16x16x32_bf16(af[m], bfv[n], acc[m][n], 0, 0, 0);
    }
  };

  int cur = 0;
  stage(0, 0);
  __syncthreads();
  for (int k0 = 0; k0 < 1024; k0 += BK) {
    if (k0 + BK < 1024) stage(cur ^ 1, k0 + BK);
    compute(cur);
    __syncthreads();
    cur ^= 1;
  }

  int cr = bm + wr + fg * 4, cc = bn + wc + fr;
  #pragma unroll
  for (int m = 0; m < 2; ++m)
    #pragma unroll
    for (int n = 0; n < 4; ++n)
      #pragma unroll
      for (int i = 0; i < 4; ++i) {
        long row = cr + m * 16 + i;
        long col = cc + n * 16;
        float v = acc[m][n][i];
        if (col < 2048) v = gelu_f(v);
        Cb[row * 5120 + col] = f2bf(v);
      }
}

// ---- qkv GEMM (768 blocks) + deferred weight transposes (4608 dual blocks) --
// bid < 768: proven BK=64 512-thr body, out ld 3072, no gelu (cols=24, rows=32).
// bid >= 768: 2x 32x32 fp32->bf16 transpose tiles (tid>>8 halves), covering
// out_w/ew1/wq/wk/wv/ew2/wo (9216 tiles); consumers are >=3 dispatches later.
struct QPack {
  const float *out_w, *ew1, *wq, *wk, *wv, *ew2, *wo;
  unsigned short *w_outt, *w_tiert, *w_ew2t, *w_wot;
};
__global__ __launch_bounds__(512) void k_qkv512(
    const unsigned short* __restrict__ A,
    const unsigned short* __restrict__ Bt,
    unsigned short* __restrict__ Cb, QPack qp)
{
  constexpr int BK = 64;
  __shared__ unsigned short As[2][128 * BK];
  __shared__ unsigned short Bs[2][128 * BK];
  int bid = blockIdx.x;
  int tid = threadIdx.x;

  if (bid >= 768) {
    int sub = tid & 255, half = tid >> 8;
    int g = (bid - 768) * 2 + half;          // [0, 9216)
    const float* in; unsigned short* out; int R, C, bx, base;
    if (g < 1024)      { in = qp.out_w; out = qp.w_outt;                   R = 1024; C = 1024; bx = 32; base = 0; }
    else if (g < 3072) { in = qp.ew1;   out = qp.w_tiert;                  R = 1024; C = 2048; bx = 64; base = 1024; }
    else if (g < 4096) { in = qp.wq;    out = qp.w_tiert + 2048*1024;      R = 1024; C = 1024; bx = 32; base = 3072; }
    else if (g < 5120) { in = qp.wk;    out = qp.w_tiert + 3072*1024;      R = 1024; C = 1024; bx = 32; base = 4096; }
    else if (g < 6144) { in = qp.wv;    out = qp.w_tiert + (size_t)4096*1024; R = 1024; C = 1024; bx = 32; base = 5120; }
    else if (g < 8192) { in = qp.ew2;   out = qp.w_ew2t;                   R = 2048; C = 1024; bx = 32; base = 6144; }
    else               { in = qp.wo;    out = qp.w_wot;                    R = 1024; C = 1024; bx = 32; base = 8192; }
    int rel = g - base;
    int c0 = (rel % bx) * 32, r0 = (rel / bx) * 32;
    int tx = sub & 31, ty = sub >> 5;
    float* T = reinterpret_cast<float*>(&As[0][0]) + half * 1100;  // 32x33 fp32 per half
    #pragma unroll
    for (int i = 0; i < 32; i += 8)
      T[(ty + i) * 33 + tx] = in[(long)(r0 + ty + i) * C + c0 + tx];
    __syncthreads();
    #pragma unroll
    for (int i = 0; i < 32; i += 8)
      out[(long)(c0 + ty + i) * R + r0 + tx] = f2bf(T[tx * 33 + (ty + i)]);
    return;
  }

  // GEMM path: 1-D grid, hardcoded cols=24, rows=32, nwg=768
  int lin = bid;
  lin = (lin & 7) * 96 + (lin >> 3);          // T1 XCD chunk (768/8=96)
  int gid = lin / 192;                         // in_grp = 8*24
  int fm = gid * 8;
  int rem = lin - gid * 192;
  int pm = fm + (rem % 8);                     // gsz = 8 (rows=32)
  int pn = rem / 8;
  int bm = pm * 128, bn = pn * 128;

  int w = tid >> 6, lane = tid & 63;
  int fr = lane & 15, fg = lane >> 4;
  int sw = (fr & 7) * 8;
  int wr = (w >> 1) * 32, wc = (w & 1) * 64;
  int lrow = lane >> 3;
  int lcol = ((lane & 7) ^ lrow) * 8;

  const unsigned short* AgJ[2];
  const unsigned short* BgJ[2];
  int OffJ[2];
  #pragma unroll
  for (int j = 0; j < 2; ++j) {
    AgJ[j] = A  + (long)(bm + j * 64 + w * 8 + lrow) * 1024 + lcol;
    BgJ[j] = Bt + (long)(bn + j * 64 + w * 8 + lrow) * 1024 + lcol;
    OffJ[j] = (j * 64 + w * 8) * BK;
  }

  f4v acc[2][4];
  #pragma unroll
  for (int m = 0; m < 2; ++m)
    #pragma unroll
    for (int n = 0; n < 4; ++n)
      acc[m][n] = (f4v){0.f, 0.f, 0.f, 0.f};

  auto stage = [&](int buf, int k0){
    #pragma unroll
    for (int j = 0; j < 2; ++j) gl16(AgJ[j] + k0, &As[buf][OffJ[j]]);
    #pragma unroll
    for (int j = 0; j < 2; ++j) gl16(BgJ[j] + k0, &Bs[buf][OffJ[j]]);
  };
  auto compute = [&](int buf){
    #pragma unroll
    for (int kk = 0; kk < 2; ++kk) {
      int kg = (kk * 32 + fg * 8) ^ sw;
      s8v af[2], bfv[4];
      #pragma unroll
      for (int m = 0; m < 2; ++m) af[m]  = *(const s8v*)&As[buf][(wr + m * 16 + fr) * BK + kg];
      #pragma unroll
      for (int n = 0; n < 4; ++n) bfv[n] = *(const s8v*)&Bs[buf][(wc + n * 16 + fr) * BK + kg];
      #pragma unroll
      for (int m = 0; m < 2; ++m)
        #pragma unroll
        for (int n = 0; n < 4; ++n)
          acc[m][n] = __builtin_amdgcn_mfma_f32_16x16x32_bf16(af[m], bfv[n], acc[m][n], 0, 0, 0);
    }
  };

  int cur = 0;
  stage(0, 0);
  __syncthreads();
  for (int k0 = 0; k0 < 1024; k0 += BK) {
    if (k0 + BK < 1024) stage(cur ^ 1, k0 + BK);
    compute(cur);
    __syncthreads();
    cur ^= 1;
  }

  int cr = bm + wr + fg * 4, cc = bn + wc + fr;
  #pragma unroll
  for (int m = 0; m < 2; ++m)
    #pragma unroll
    for (int n = 0; n < 4; ++n)
      #pragma unroll
      for (int i = 0; i < 4; ++i) {
        long row = cr + m * 16 + i;
        long col = cc + n * 16;
        Cb[row * 3072 + col] = f2bf(acc[m][n][i]);
      }
}

// ---- qkv split: RoPE + V transpose (bf16 input, r3-proven) ------------------
// grid (T/32, BH), 256 thr. Qb/Kb: [bh][t][64] (Q scaled 1/8). Vt: [bh][64][t].
__global__ __launch_bounds__(256) void k_qkvsplit(const unsigned short* __restrict__ qkv,
    unsigned short* __restrict__ Qb, unsigned short* __restrict__ Kb,
    unsigned short* __restrict__ Vt)
{
  __shared__ unsigned short vt_s[64][40];
  int t0 = blockIdx.x * 32;
  int bh = blockIdx.y;
  int b = bh >> 4, h = bh & 15;
  int tid = threadIdx.x;
  int tl = tid >> 3, jb = (tid & 7) * 4;
  int t = t0 + tl;
  long base = ((long)(b * Tz + t)) * 3072 + h * 64;
  float cs[4], sn[4];
  #pragma unroll
  for (int ii = 0; ii < 4; ++ii) {
    float inv = exp2f(-(float)(jb + ii) * 0.41524101186092030f);
    sincosf((float)t * inv, &sn[ii], &cs[ii]);
  }
  ushort4 q1 = *(const ushort4*)(qkv + base + jb);
  ushort4 q2 = *(const ushort4*)(qkv + base + jb + 32);
  ushort4 k1 = *(const ushort4*)(qkv + base + 1024 + jb);
  ushort4 k2 = *(const ushort4*)(qkv + base + 1024 + jb + 32);
  ushort4 v1 = *(const ushort4*)(qkv + base + 2048 + jb);
  ushort4 v2 = *(const ushort4*)(qkv + base + 2048 + jb + 32);
  float q1a[4] = {bf2f(q1.x), bf2f(q1.y), bf2f(q1.z), bf2f(q1.w)};
  float q2a[4] = {bf2f(q2.x), bf2f(q2.y), bf2f(q2.z), bf2f(q2.w)};
  float k1a[4] = {bf2f(k1.x), bf2f(k1.y), bf2f(k1.z), bf2f(k1.w)};
  float k2a[4] = {bf2f(k2.x), bf2f(k2.y), bf2f(k2.z), bf2f(k2.w)};
  unsigned short va[4] = {v1.x, v1.y, v1.z, v1.w};
  unsigned short vb[4] = {v2.x, v2.y, v2.z, v2.w};
  unsigned short qo1[4], qo2[4], ko1[4], ko2[4];
  #pragma unroll
  for (int ii = 0; ii < 4; ++ii) {
    qo1[ii] = f2bf((q1a[ii] * cs[ii] - q2a[ii] * sn[ii]) * 0.125f);
    qo2[ii] = f2bf((q1a[ii] * sn[ii] + q2a[ii] * cs[ii]) * 0.125f);
    ko1[ii] = f2bf(k1a[ii] * cs[ii] - k2a[ii] * sn[ii]);
    ko2[ii] = f2bf(k1a[ii] * sn[ii] + k2a[ii] * cs[ii]);
    vt_s[jb + ii][tl]      = va[ii];
    vt_s[jb + 32 + ii][tl] = vb[ii];
  }
  long ob = (long)bh * Tz * 64 + (long)t * 64;
  *(ushort4*)(Qb + ob + jb)      = *(ushort4*)qo1;
  *(ushort4*)(Qb + ob + jb + 32) = *(ushort4*)qo2;
  *(ushort4*)(Kb + ob + jb)      = *(ushort4*)ko1;
  *(ushort4*)(Kb + ob + jb + 32) = *(ushort4*)ko2;
  __syncthreads();
  int d = tid >> 2, tc = (tid & 3) * 8;
  *(uint4*)(Vt + (long)bh * 64 * Tz + (long)d * Tz + t0 + tc) = *(const uint4*)&vt_s[d][tc];
}

// ---- merged tail: ew2 split-K (512) + attn2 S lower-tri (144) + V-transpose
// (256) in one dispatch; all three read disjoint tierb columns, outputs
// disjoint, consumers all later in stream.
__global__ __launch_bounds__(512) void k_tail512(
    const unsigned short* __restrict__ tierb,
    const unsigned short* __restrict__ w_ew2t,
    unsigned short* __restrict__ eo, long eoDelta,
    unsigned short* __restrict__ Sb,
    unsigned short* __restrict__ v2t)
{
  constexpr int BK = 64;
  __shared__ unsigned short As[2][128 * BK];
  __shared__ unsigned short Bs[2][128 * BK];
  int bid = blockIdx.x;
  int tid = threadIdx.x;

  if (bid >= 656) {
    // V transpose: in = tierb cols [4096,5120) (ld 5120) -> v2t [d][t] (ld 1024)
    int g0 = (bid - 656) * 16;
    int sub = tid & 255, half = tid >> 8;
    int tx = sub & 31, ty = sub >> 5;
    unsigned short* T = &As[0][0] + half * 1100;   // 32x33 scratch per half
    for (int it = 0; it < 8; ++it) {
      int g = g0 + half * 8 + it;
      int z = g >> 10, rem = g & 1023;
      int r0 = (rem >> 5) * 32, c0 = (rem & 31) * 32;
      const unsigned short* inp = tierb + 4096 + (long)z * ((long)Tz * 5120);
      unsigned short* outp = v2t + (long)z * ((long)Tz * 1024);
      #pragma unroll
      for (int i = 0; i < 32; i += 8)
        T[(ty + i) * 33 + tx] = inp[(long)(r0 + ty + i) * 5120 + c0 + tx];
      __syncthreads();
      #pragma unroll
      for (int i = 0; i < 32; i += 8)
        outp[(long)(c0 + ty + i) * 1024 + r0 + tx] = T[tx * 33 + (ty + i)];
      __syncthreads();
    }
    return;
  }

  int w = tid >> 6, lane = tid & 63;
  int fr = lane & 15, fg = lane >> 4;
  int sw = (fr & 7) * 8;
  int wr = (w >> 1) * 32, wc = (w & 1) * 64;
  int lrow = lane >> 3;
  int lcol = ((lane & 7) ^ lrow) * 8;

  const unsigned short* A;
  const unsigned short* Bt;
  unsigned short* Cout;
  long ldA, ldB;
  int bm, bn;
  float scale;
  if (bid < 512) {
    int z = bid >> 8;
    int lin = bid & 255;
    lin = (lin & 7) * 32 + (lin >> 3);       // T1 swizzle, nwg=256
    int gid = lin / 64;                       // in_grp = 8*cols = 64
    int fm = gid * 8;
    int rem = lin - gid * 64;
    int pm = fm + (rem & 7);                  // gsz = 8 always (rows=32)
    int pn = rem >> 3;
    bm = pm * 128; bn = pn * 128;
    A    = tierb + (long)z * 1024;
    Bt   = w_ew2t + (long)z * 1024;
    Cout = eo + (long)z * eoDelta;
    ldA = 5120; ldB = 2048;
    scale = 1.0f;
  } else {
    int r2 = bid - 512;
    int li = r2 % 36;
    int z  = r2 / 36;
    int r = (int)((sqrtf(8.f * li + 1.f) - 1.f) * 0.5f);
    if ((r + 1) * (r + 2) / 2 <= li) ++r;
    if (r * (r + 1) / 2 > li) --r;
    bm = r * 128; bn = (li - r * (r + 1) / 2) * 128;
    A    = tierb + 2048 + (long)z * ((long)Tz * 5120);
    Bt   = tierb + 3072 + (long)z * ((long)Tz * 5120);
    Cout = Sb + (long)z * ((long)Tz * Tz);
    ldA = 5120; ldB = 5120;
    scale = 0.03125f;
  }

  const unsigned short* AgJ[2];
  const unsigned short* BgJ[2];
  int OffJ[2];
  #pragma unroll
  for (int j = 0; j < 2; ++j) {
    AgJ[j] = A  + (long)(bm + j * 64 + w * 8 + lrow) * ldA + lcol;
    BgJ[j] = Bt + (long)(bn + j * 64 + w * 8 + lrow) * ldB + lcol;
    OffJ[j] = (j * 64 + w * 8) * BK;
  }

  f4v acc[2][4];
  #pragma unroll
  for (int m = 0; m < 2; ++m)
    #pragma unroll
    for (int n = 0; n < 4; ++n)
      acc[m][n] = (f4v){0.f, 0.f, 0.f, 0.f};

  auto stage = [&](int buf, int k0){
    #pragma unroll
    for (int j = 0; j < 2; ++j) gl16(AgJ[j] + k0, &As[buf][OffJ[j]]);
    #pragma unroll
    for (int j = 0; j < 2; ++j) gl16(BgJ[j] + k0, &Bs[buf][OffJ[j]]);
  };
  auto compute = [&](int buf){
    #pragma unroll
    for (int kk = 0; kk < 2; ++kk) {
      int kg = (kk * 32 + fg * 8) ^ sw;
      s8v af[2], bfv[4];
      #pragma unroll
      for (int m = 0; m < 2; ++m) af[m]  = *(const s8v*)&As[buf][(wr + m * 16 + fr) * BK + kg];
      #pragma unroll
      for (int n = 0; n < 4; ++n) bfv[n] = *(const s8v*)&Bs[buf][(wc + n * 16 + fr) * BK + kg];
      #pragma unroll
      for (int m = 0; m < 2; ++m)
        #pragma unroll
        for (int n = 0; n < 4; ++n)
          acc[m][n] = __builtin_amdgcn_mfma_f32_16x16x32_bf16(af[m], bfv[n], acc[m][n], 0, 0, 0);
    }
  };

  int cur = 0;
  stage(0, 0);
  __syncthreads();
  for (int k0 = 0; k0 < 1024; k0 += BK) {
    if (k0 + BK < 1024) stage(cur ^ 1, k0 + BK);
    compute(cur);
    __syncthreads();
    cur ^= 1;
  }

  int cr = bm + wr + fg * 4, cc = bn + wc + fr;
  #pragma unroll
  for (int m = 0; m < 2; ++m)
    #pragma unroll
    for (int n = 0; n < 4; ++n)
      #pragma unroll
      for (int i = 0; i < 4; ++i) {
        long row = cr + m * 16 + i;
        long col = cc + n * 16;
        Cout[row * 1024 + col] = f2bf(acc[m][n][i] * scale);
      }
}

// ---- wo GEMM, 512-thread split-K clone: C(4096x1024), K=1024 -> 2x512 -------
__global__ __launch_bounds__(512) void k_wo512(
    const unsigned short* __restrict__ A,
    const unsigned short* __restrict__ Bt,
    unsigned short* __restrict__ Cb, long sC)
{
  constexpr int BK = 64;
  __shared__ unsigned short As[2][128 * BK];
  __shared__ unsigned short Bs[2][128 * BK];
  A  += (long)blockIdx.z * 512;
  Bt += (long)blockIdx.z * 512;
  Cb += (long)blockIdx.z * sC;
  int lin = blockIdx.y * gridDim.x + blockIdx.x;
  int cols = gridDim.x, rows = gridDim.y;
  int nwg = cols * rows;
  if ((nwg & 7) == 0) lin = (lin & 7) * (nwg >> 3) + (lin >> 3);
  int in_grp = 8 * cols;
  int gid = lin / in_grp;
  int fm = gid * 8;
  int gsz = min(rows - fm, 8);
  int rem = lin - gid * in_grp;
  int pm = fm + (rem % gsz);
  int pn = rem / gsz;
  int bm = pm * 128, bn = pn * 128;

  int tid = threadIdx.x, w = tid >> 6, lane = tid & 63;
  int fr = lane & 15, fg = lane >> 4;
  int sw = (fr & 7) * 8;
  int wr = (w >> 1) * 32, wc = (w & 1) * 64;
  int lrow = lane >> 3;
  int lcol = ((lane & 7) ^ lrow) * 8;

  const unsigned short* AgJ[2];
  const unsigned short* BgJ[2];
  int OffJ[2];
  #pragma unroll
  for (int j = 0; j < 2; ++j) {
    AgJ[j] = A  + (long)(bm + j * 64 + w * 8 + lrow) * 1024 + lcol;
    BgJ[j] = Bt + (long)(bn + j * 64 + w * 8 + lrow) * 1024 + lcol;
    OffJ[j] = (j * 64 + w * 8) * BK;
  }

  f4v acc[2][4];
  #pragma unroll
  for (int m = 0; m < 2; ++m)
    #pragma unroll
    for (int n = 0; n < 4; ++n)
      acc[m][n] = (f4v){0.f, 0.f, 0.f, 0.f};

  auto stage = [&](int buf, int k0){
    #pragma unroll
    for (int j = 0; j < 2; ++j) gl16(AgJ[j] + k0, &As[buf][OffJ[j]]);
    #pragma unroll
    for (int j = 0; j < 2; ++j) gl16(BgJ[j] + k0, &Bs[buf][OffJ[j]]);
  };
  auto compute = [&](int buf){
    #pragma unroll
    for (int kk = 0; kk < 2; ++kk) {
      int kg = (kk * 32 + fg * 8) ^ sw;
      s8v af[2], bfv[4];
      #pragma unroll
      for (int m = 0; m < 2; ++m) af[m]  = *(const s8v*)&As[buf][(wr + m * 16 + fr) * BK + kg];
      #pragma unroll
      for (int n = 0; n < 4; ++n) bfv[n] = *(const s8v*)&Bs[buf][(wc + n * 16 + fr) * BK + kg];
      #pragma unroll
      for (int m = 0; m < 2; ++m)
        #pragma unroll
        for (int n = 0; n < 4; ++n)
          acc[m][n] = __builtin_amdgcn_mfma_f32_16x16x32_bf16(af[m], bfv[n], acc[m][n], 0, 0, 0);
    }
  };

  int cur = 0;
  stage(0, 0);
  __syncthreads();
  for (int k0 = 0; k0 < 512; k0 += BK) {
    if (k0 + BK < 512) stage(cur ^ 1, k0 + BK);
    compute(cur);
    __syncthreads();
    cur ^= 1;
  }

  int cr = bm + wr + fg * 4, cc = bn + wc + fr;
  #pragma unroll
  for (int m = 0; m < 2; ++m)
    #pragma unroll
    for (int n = 0; n < 4; ++n)
      #pragma unroll
      for (int i = 0; i < 4; ++i) {
        long row = cr + m * 16 + i;
        long col = cc + n * 16;
        Cb[row * 1024 + col] = f2bf(acc[m][n][i]);
      }
}

// ---------------- GEMM: C = A(MxK,bf16,lda) @ Bt(NxK,bf16,ldb)^T -------------
// m97 structure + T2 XOR-swizzle + T1 XCD chunk + grouped-M (GM=8) ordering.
// DBUF: 2-phase pipeline. MODE 0: fp32  1: fp32+addsrc  3: bf16
// 6: bf16(v/32)  7: bf16(acc+addsrc).  TRIMAP (BN=64): lower-tri tiles
// c<=2r+1.  TRIK: Keff=bm+128, heavy first.
template<int MODE, int BN, bool TRIMAP, bool TRIK, bool DBUF>
__global__ __launch_bounds__(256) void k_gemm(
    const unsigned short* __restrict__ A,
    const unsigned short* __restrict__ Bt,
    float* __restrict__ Cf, unsigned short* __restrict__ Cb,
    const float* __restrict__ addsrc,
    unsigned short* __restrict__ P1, unsigned short* __restrict__ P2,
    int N, int K, int lda, int ldb,
    long sA, long sB, long sC)
{
  constexpr int BM = 128;
  constexpr int MREP = (BN == 128) ? 4 : 2;
  constexpr int NB = DBUF ? 2 : 1;
  __shared__ unsigned short As[NB][BM * 64];
  __shared__ unsigned short Bs[NB][BN * 64];
  int bm, bn;
  if (TRIMAP) {
    int li = blockIdx.x;
    int nwg = gridDim.x;
    if ((nwg & 7) == 0) li = (li & 7) * (nwg >> 3) + (li >> 3);   // T1
    int r = (int)((sqrtf(4.f * li + 1.f) - 1.f) * 0.5f);
    if ((r + 1) * (r + 2) <= li) ++r;
    if (r * (r + 1) > li) --r;
    bm = r * 128; bn = (li - r * (r + 1)) * BN;
  } else {
    int lin = blockIdx.y * gridDim.x + blockIdx.x;
    int nwg = gridDim.x * gridDim.y;
    if ((nwg & 7) == 0) lin = (lin & 7) * (nwg >> 3) + (lin >> 3); // T1 XCD chunk
    int cols = gridDim.x, rows = gridDim.y;
    constexpr int GM = 8;
    int in_grp = GM * cols;
    int gid = lin / in_grp;
    int fm = gid * GM;
    int gsz = min(rows - fm, GM);
    int rem = lin - gid * in_grp;
    int pm = fm + (rem % gsz);
    int pn = rem / gsz;
    if (TRIK) pm = rows - 1 - pm;     // heavy (large Keff) first
    bm = pm * BM; bn = pn * BN;
  }
  A  += (long)blockIdx.z * sA;
  Bt += (long)blockIdx.z * sB;
  int tid = threadIdx.x, w = tid >> 6, lane = tid & 63;
  int wr, wc;
  if (BN == 128) { wr = (w >> 1) * 64; wc = (w & 1) * 64; }
  else           { wr = w * 32;        wc = 0; }
  f4v acc[MREP][4];
  #pragma unroll
  for (int m = 0; m < MREP; ++m)
    #pragma unroll
    for (int n = 0; n < 4; ++n)
      acc[m][n] = (f4v){0.f, 0.f, 0.f, 0.f};

  int Keff = K;
  if (TRIK) Keff = min(K, bm + BM);

  int lrow = lane >> 3;
  int lcol = (((lane & 7) ^ lrow) * 8);
  const unsigned short* AgJ[4];
  int AsOff[4];
  #pragma unroll
  for (int j = 0; j < 4; ++j) {
    AgJ[j] = A + (long)(bm + w * 32 + j * 8 + lrow) * lda + lcol;
    AsOff[j] = (w * 32 + j * 8) * 64;
  }
  constexpr int BCH = BN / 8 / 4;
  const unsigned short* BgJ[BCH];
  int BsOff[BCH];
  #pragma unroll
  for (int j = 0; j < BCH; ++j) {
    BgJ[j] = Bt + (long)(bn + w * (BCH * 8) + j * 8 + lrow) * ldb + lcol;
    BsOff[j] = (w * (BCH * 8) + j * 8) * 64;
  }

  int fr = lane & 15, fg = lane >> 4;
  int sw = (fr & 7) * 8;

  auto stage = [&](int buf, int k0){
    #pragma unroll
    for (int j = 0; j < 4; ++j) gl16(AgJ[j] + k0, &As[buf][AsOff[j]]);
    #pragma unroll
    for (int j = 0; j < BCH; ++j) gl16(BgJ[j] + k0, &Bs[buf][BsOff[j]]);
  };
  auto compute = [&](int buf){
    #pragma unroll
    for (int kk = 0; kk < 2; ++kk) {
      int kg = (kk * 32 + fg * 8) ^ sw;
      s8v af[MREP], bfv[4];
      #pragma unroll
      for (int m = 0; m < MREP; ++m) af[m]  = *(const s8v*)&As[buf][(wr + m * 16 + fr) * 64 + kg];
      #pragma unroll
      for (int n = 0; n < 4; ++n)    bfv[n] = *(const s8v*)&Bs[buf][(wc + n * 16 + fr) * 64 + kg];
      #pragma unroll
      for (int m = 0; m < MREP; ++m)
        #pragma unroll
        for (int n = 0; n < 4; ++n)
          acc[m][n] = __builtin_amdgcn_mfma_f32_16x16x32_bf16(af[m], bfv[n], acc[m][n], 0, 0, 0);
    }
  };

  if (DBUF) {
    int cur = 0;
    stage(0, 0);
    __syncthreads();
    for (int k0 = 0; k0 < Keff; k0 += 64) {
      if (k0 + 64 < Keff) stage(cur ^ 1, k0 + 64);
      compute(cur);
      __syncthreads();
      cur ^= 1;
    }
  } else {
    for (int k0 = 0; k0 < Keff; k0 += 64) {
      __syncthreads();
      stage(0, k0);
      __syncthreads();
      compute(0);
    }
  }

  int cr0 = bm + wr + fg * 4;
  int cc0 = bn + wc + fr;

  #pragma unroll
  for (int m = 0; m < MREP; ++m)
    #pragma unroll
    for (int n = 0; n < 4; ++n)
      #pragma unroll
      for (int i = 0; i < 4; ++i) {
        long row = cr0 + m * 16 + i, col = cc0 + n * 16;
        long idx = (long)blockIdx.z * sC + row * (long)N + col;
        float v = acc[m][n][i];
        if (MODE == 1 || MODE == 7) v += addsrc[idx];
        if (MODE == 6) v *= 0.03125f;
        if (MODE <= 1) Cf[idx] = v; else Cb[idx] = f2bf(v);
      }
}

// ---------------- backbone flash attention, MFMA (hd=64) ---------------------
// heavy-first dispatch + reg-staged K/V prefetch (issue-early / write-late).
__global__ __launch_bounds__(256) void k_attn_mfma(
    const unsigned short* __restrict__ Qb, const unsigned short* __restrict__ Kb,
    const unsigned short* __restrict__ Vt, unsigned short* __restrict__ ao)
{
  __shared__ unsigned short Ks[64][72];
  __shared__ unsigned short Vs[64][72];   // Vs[d][key]
  __shared__ unsigned short Ps[4][16][72];
  int qb = 15 - (blockIdx.x >> 6);
  int bh = blockIdx.x & 63;
  int b = bh >> 4, h = bh & 15;
  int t0 = qb * 64;
  int tid = threadIdx.x, w = tid >> 6, lane = tid & 63;
  int fr = lane & 15, fg = lane >> 4;

  const unsigned short* qp = Qb + (long)bh * Tz * 64 + (long)(t0 + w * 16 + fr) * 64 + fg * 8;
  s8v qf[2] = { *(const s8v*)qp, *(const s8v*)(qp + 32) };

  f4v o_acc[4];
  #pragma unroll
  for (int n = 0; n < 4; ++n) o_acc[n] = (f4v){0.f, 0.f, 0.f, 0.f};
  float m_[4] = {-1e30f, -1e30f, -1e30f, -1e30f};
  float l_[4] = {0.f, 0.f, 0.f, 0.f};

  int sr = tid >> 3, sc = (tid & 7) * 8;
  const unsigned short* Kg = Kb + (long)bh * Tz * 64 + (long)sr * 64 + sc;
  const unsigned short* Vg = Vt + (long)bh * 64 * Tz + (long)sr * Tz + sc;

  uint4 pk0, pk1, pv0, pv1;
  auto loadregs = [&](int k0){
    pk0 = *(const uint4*)(Kg + (long)k0 * 64);
    pk1 = *(const uint4*)(Kg + (long)(k0 + 32) * 64);
    pv0 = *(const uint4*)(Vg + k0);
    pv1 = *(const uint4*)(Vg + (long)32 * Tz + k0);
  };
  auto storelds = [&](){
    *(uint4*)&Ks[sr][sc]      = pk0;
    *(uint4*)&Ks[sr + 32][sc] = pk1;
    *(uint4*)&Vs[sr][sc]      = pv0;
    *(uint4*)&Vs[sr + 32][sc] = pv1;
  };

  loadregs(0);
  storelds();
  __syncthreads();

  for (int kt = 0; kt <= qb; ++kt) {
    int k0 = kt * 64;
    if (kt < qb) loadregs(k0 + 64);   // issue next tile's loads early

    f4v sacc[4];
    #pragma unroll
    for (int n = 0; n < 4; ++n) sacc[n] = (f4v){0.f, 0.f, 0.f, 0.f};
    #pragma unroll
    for (int kk = 0; kk < 2; ++kk) {
      int kg = kk * 32 + fg * 8;
      #pragma unroll
      for (int n = 0; n < 4; ++n) {
        s8v bf = *(const s8v*)&Ks[n * 16 + fr][kg];
        sacc[n] = __builtin_amdgcn_mfma_f32_16x16x32_bf16(qf[kk], bf, sacc[n], 0, 0, 0);
      }
    }

    bool full = (kt < qb);
    float p[4][4], alpha[4];
    #pragma unroll
    for (int i = 0; i < 4; ++i) {
      int trow = t0 + w * 16 + fg * 4 + i;
      float mx = -1e30f;
      #pragma unroll
      for (int n = 0; n < 4; ++n) {
        float sval = sacc[n][i];
        if (!full) {
          int key = k0 + n * 16 + fr;
          sval = (key <= trow) ? sval : -1e30f;
        }
        p[n][i] = sval;
        mx = fmaxf(mx, sval);
      }
      mx = fmaxf(mx, __shfl_xor(mx, 1));
      mx = fmaxf(mx, __shfl_xor(mx, 2));
      mx = fmaxf(mx, __shfl_xor(mx, 4));
      mx = fmaxf(mx, __shfl_xor(mx, 8));
      float mnew = fmaxf(m_[i], mx);
      alpha[i] = __expf(m_[i] - mnew);
      m_[i] = mnew;
      float ps = 0.f;
      #pragma unroll
      for (int n = 0; n < 4; ++n) {
        float pv = __expf(p[n][i] - mnew);
        p[n][i] = pv;
        ps += pv;
      }
      ps += __shfl_xor(ps, 1); ps += __shfl_xor(ps, 2);
      ps += __shfl_xor(ps, 4); ps += __shfl_xor(ps, 8);
      l_[i] = l_[i] * alpha[i] + ps;
    }
    #pragma unroll
    for (int n = 0; n < 4; ++n)
      #pragma unroll
      for (int i = 0; i < 4; ++i)
        o_acc[n][i] *= alpha[i];
    #pragma unroll
    for (int n = 0; n < 4; ++n)
      #pragma unroll
      for (int i = 0; i < 4; ++i)
        Ps[w][fg * 4 + i][n * 16 + fr] = f2bf(p[n][i]);

    #pragma unroll
    for (int kk = 0; kk < 2; ++kk) {
      int kg = kk * 32 + fg * 8;
      s8v pa = *(const s8v*)&Ps[w][fr][kg];
      #pragma unroll
      for (int n = 0; n < 4; ++n) {
        s8v vb = *(const s8v*)&Vs[n * 16 + fr][kg];
        o_acc[n] = __builtin_amdgcn_mfma_f32_16x16x32_bf16(pa, vb, o_acc[n], 0, 0, 0);
      }
    }

    if (kt < qb) {
      __syncthreads();   // all waves done reading Ks/Vs
      storelds();        // write prefetched tile (single LDS buffer)
      __syncthreads();   // writes visible
    }
  }

  float inv[4];
  #pragma unroll
  for (int i = 0; i < 4; ++i) inv[i] = 1.0f / l_[i];
  #pragma unroll
  for (int n = 0; n < 4; ++n)
    #pragma unroll
    for (int i = 0; i < 4; ++i) {
      int t = t0 + w * 16 + fg * 4 + i;
      ao[((long)(b * Tz + t)) * Dz + h * 64 + n * 16 + fr] = f2bf(o_acc[n][i] * inv[i]);
    }
}

// ---------------- causal softmax (attn2): S bf16 -> P bf16 -------------------
__global__ __launch_bounds__(256) void k_softmax_causal(const unsigned short* __restrict__ S,
    unsigned short* __restrict__ P)
{
  long row = blockIdx.x;
  int t = (int)(row & (Tz - 1));
  int tid = threadIdx.x;
  const unsigned short* sp = S + row * Tz;
  ushort4 v = ((const ushort4*)sp)[tid];
  float vv[4];
  vv[0] = (tid*4 + 0 <= t) ? bf2f(v.x) : -1e30f;
  vv[1] = (tid*4 + 1 <= t) ? bf2f(v.y) : -1e30f;
  vv[2] = (tid*4 + 2 <= t) ? bf2f(v.z) : -1e30f;
  vv[3] = (tid*4 + 3 <= t) ? bf2f(v.w) : -1e30f;
  float mx = fmaxf(fmaxf(vv[0], vv[1]), fmaxf(vv[2], vv[3]));
  int lane = tid & 63, wv = tid >> 6;
  #pragma unroll
  for (int off = 32; off; off >>= 1) mx = fmaxf(mx, __shfl_xor(mx, off));
  __shared__ float red[8];
  if (lane == 0) red[wv] = mx;
  __syncthreads();
  mx = fmaxf(fmaxf(red[0], red[1]), fmaxf(red[2], red[3]));
  float p[4];
  float s = 0.f;
  #pragma unroll
  for (int i = 0; i < 4; ++i){ p[i] = __expf(vv[i] - mx); s += p[i]; }
  #pragma unroll
  for (int off = 32; off; off >>= 1) s += __shfl_xor(s, off);
  if (lane == 0) red[4 + wv] = s;
  __syncthreads();
  s = red[4] + red[5] + red[6] + red[7];
  float inv = 1.0f / s;
  ushort4 ov;
  ov.x = f2bf(p[0] * inv); ov.y = f2bf(p[1] * inv);
  ov.z = f2bf(p[2] * inv); ov.w = f2bf(p[3] * inv);
  *((ushort4*)(P + row * Tz) + tid) = ov;
}

// ---------------- fused conv tier + combine + sink scale ---------------------
__global__ __launch_bounds__(256) void k_combine(
    const unsigned short* __restrict__ x2, const unsigned short* __restrict__ hbf,
    const unsigned short* __restrict__ eoa, const unsigned short* __restrict__ eob,
    const unsigned short* __restrict__ ap, const unsigned short* __restrict__ ap2,
    const float* __restrict__ rout, const float* __restrict__ convw,
    const float* __restrict__ tg, const float* __restrict__ sinkp,
    float* __restrict__ outx)
{
  int row = blockIdx.x, tid = threadIdx.x;
  int t = row & (Tz - 1), b = row >> 10;
  int d0 = tid * 4;
  ushort4 xu = *(const ushort4*)(x2 + (long)row * Dz + d0);
  ushort4 ea = *(const ushort4*)(eoa + (long)row * Dz + d0);
  ushort4 eb = *(const ushort4*)(eob + (long)row * Dz + d0);
  ushort4 a4 = *(const ushort4*)(ap + (long)row * Dz + d0);
  ushort4 a42 = *(const ushort4*)(ap2 + (long)row * Dz + d0);
  float4 t4 = *(const float4*)(tg + d0);
  float4 r4 = *(const float4*)(rout + (long)row * 4);
  float sks = fabsf(sinkp[0]);
  float kv = 1.0f - r4.w * (1.0f - sks);
  const float4* cwp = (const float4*)(convw + (long)d0 * 3);
  float4 c0 = cwp[0], c1 = cwp[1], c2 = cwp[2];
  float cwf[12] = {c0.x, c0.y, c0.z, c0.w, c1.x, c1.y, c1.z, c1.w, c2.x, c2.y, c2.z, c2.w};
  float hv[3][4];
  #pragma unroll
  for (int tap = 0; tap < 3; ++tap) {
    int tt = t - 2 + tap;
    if (tt >= 0) {
      ushort4 hu = *((const ushort4*)(hbf + ((long)(b * Tz + tt)) * Dz + d0));
      hv[tap][0] = bf2f(hu.x); hv[tap][1] = bf2f(hu.y);
      hv[tap][2] = bf2f(hu.z); hv[tap][3] = bf2f(hu.w);
    } else {
      hv[tap][0] = 0.f; hv[tap][1] = 0.f; hv[tap][2] = 0.f; hv[tap][3] = 0.f;
    }
  }
  float ov[4];
  float xi[4] = {bf2f(xu.x), bf2f(xu.y), bf2f(xu.z), bf2f(xu.w)};
  float ei[4] = {bf2f(ea.x) + bf2f(eb.x), bf2f(ea.y) + bf2f(eb.y),
                 bf2f(ea.z) + bf2f(eb.z), bf2f(ea.w) + bf2f(eb.w)};
  float ai[4] = {bf2f(a4.x) + bf2f(a42.x), bf2f(a4.y) + bf2f(a42.y),
                 bf2f(a4.z) + bf2f(a42.z), bf2f(a4.w) + bf2f(a42.w)};
  float ti[4] = {t4.x, t4.y, t4.z, t4.w};
  #pragma unroll
  for (int i = 0; i < 4; ++i) {
    float conv = hv[0][i] * cwf[i*3 + 0] + hv[1][i] * cwf[i*3 + 1] + hv[2][i] * cwf[i*3 + 2];
    float comb = gelu_f(conv) * r4.x + ei[i] * r4.y + ai[i] * r4.z;
    ov[i] = (xi[i] + comb * ti[i]) * kv;
  }
  float4 res = {ov[0], ov[1], ov[2], ov[3]};
  *(float4*)(outx + (long)row * Dz + d0) = res;
}

// ---------------- host launcher ----------------------------------------------
extern "C" void kernel_launch(void* const* d_in, const int* in_sizes, int n_in,
                              void* d_out, int out_size, void* d_ws, size_t ws_size,
                              hipStream_t stream) {
  (void)in_sizes; (void)n_in; (void)out_size; (void)ws_size;
  const float* x       = (const float*)d_in[0];
  const float* ln1_w   = (const float*)d_in[1];
  const float* ln1_b   = (const float*)d_in[2];
  const float* qkv_w   = (const float*)d_in[3];
  const float* out_w   = (const float*)d_in[4];
  const float* ln2_w   = (const float*)d_in[5];
  const float* ln2_b   = (const float*)d_in[6];
  const float* router_w= (const float*)d_in[7];
  const float* conv_w  = (const float*)d_in[8];
  const float* ew1     = (const float*)d_in[9];
  const float* ew2     = (const float*)d_in[10];
  const float* at_wq   = (const float*)d_in[11];
  const float* at_wk   = (const float*)d_in[12];
  const float* at_wv   = (const float*)d_in[13];
  const float* at_wo   = (const float*)d_in[14];
  const float* tg      = (const float*)d_in[15];
  const float* sinkp   = (const float*)d_in[16];
  float* outx = (float*)d_out;
  float* rout = outx + (size_t)NTz * Dz;

  char* ws = (char*)d_ws;
  size_t off = 0;
  auto alloc = [&](size_t bytes) -> char* {
    char* p = ws + off;
    off += (bytes + 255) & ~(size_t)255;
    return p;
  };
  const long TD = (long)Tz * Dz, TT = (long)Tz * Tz;

  // ws budget: <= proven 159.4 MB (total ~151 MB).
  unsigned short* w_qkvt  = (unsigned short*)alloc((size_t)3072*1024*2);
  unsigned short* w_outt  = (unsigned short*)alloc((size_t)1024*1024*2);
  unsigned short* w_tiert = (unsigned short*)alloc((size_t)5120*1024*2); // [ew1|wq|wk|wv]^T
  unsigned short* w_ew2t  = (unsigned short*)alloc((size_t)1024*2048*2);
  unsigned short* w_wot   = (unsigned short*)alloc((size_t)1024*1024*2);
  unsigned short* h1bf    = (unsigned short*)alloc((size_t)NTz*Dz*2);
  unsigned short* tierb   = (unsigned short*)alloc((size_t)NTz*5120*2);  // 40 MB
  unsigned short* aobf    = (unsigned short*)alloc((size_t)NTz*Dz*2);
  unsigned short* x2b     = (unsigned short*)alloc((size_t)NTz*Dz*2);    // bf16 residual
  unsigned short* hbf     = (unsigned short*)alloc((size_t)NTz*Dz*2);
  unsigned short* Pbf     = (unsigned short*)alloc((size_t)Bz*Tz*Tz*2);
  unsigned short* v2tbf   = (unsigned short*)alloc((size_t)NTz*Dz*2);
  unsigned short* a2obf   = (unsigned short*)alloc((size_t)NTz*Dz*2);
  unsigned short* eofb    = (unsigned short*)alloc((size_t)NTz*Dz*2);    // split-K half 0
  unsigned short* a2pb    = (unsigned short*)alloc((size_t)NTz*Dz*2);
  unsigned short* Sbf     = (unsigned short*)alloc((size_t)Bz*Tz*Tz*2);  // 8 MB

  // aliases (lifetime-disjoint):
  unsigned short* qkvb = tierb;               // qkv bf16 [row][3072]; dead after
                                              // qkvsplit; tierb written later
  unsigned short* Qb = x2b;                   // x2b written by out-proj (after attn)
  unsigned short* Kb = Pbf;                   // Pbf written by softmax (after attn)
  unsigned short* Vt = a2pb;                  // a2pb written by wo GEMM (after attn)
  unsigned short* eofb2 = h1bf;               // h1bf dead after qkv GEMM; split-K half 1
  long eoDelta = (long)(eofb2 - eofb);        // z*sC lands z=1 in eofb2
  unsigned short* a2pb2 = Sbf;                // Sbf dead after softmax; wo half 1
  long woDelta = (long)(a2pb2 - a2pb);        // z*sC lands z=1 in Sbf

  dim3 blk(256);

  // head: qkv_w transpose (critical path) + LN1, one dispatch
  k_head<<<dim3(7168), blk, 0, stream>>>(qkv_w, w_qkvt, x, ln1_w, ln1_b, h1bf);

  // qkv GEMM (768 blocks) + deferred weight transposes (4608 blocks)
  QPack qp = {out_w, ew1, at_wq, at_wk, at_wv, ew2, at_wo,
              w_outt, w_tiert, w_ew2t, w_wot};
  k_qkv512<<<dim3(5376), dim3(512), 0, stream>>>(h1bf, w_qkvt, qkvb, qp);
  k_qkvsplit<<<dim3(32, 64), blk, 0, stream>>>(qkvb, Qb, Kb, Vt);
  k_attn_mfma<<<dim3(1024), blk, 0, stream>>>(Qb, Kb, Vt, aobf);
  k_gemm<7,64,false,false,true><<<dim3(16, 32), blk, 0, stream>>>(aobf, w_outt, nullptr,
      x2b, x, nullptr, nullptr, 1024, 1024, 1024, 1024, 0, 0, 0);
  // tiers
  k_ln_router<<<NTz, blk, 0, stream>>>(x2b, ln2_w, ln2_b, router_w, hbf, rout);
  k_gemm512<<<dim3(40, 32), dim3(512), 0, stream>>>(hbf, w_tiert, tierb);
  // merged tail: ew2 split-K (512) + attn2 S (144) + V2 transpose (256)
  k_tail512<<<dim3(912), dim3(512), 0, stream>>>(tierb, w_ew2t, eofb, eoDelta,
      Sbf, v2tbf);
  k_softmax_causal<<<NTz, blk, 0, stream>>>(Sbf, Pbf);
  k_gemm<3,64,false,true,true><<<dim3(16, 8, 4), blk, 0, stream>>>(Pbf, v2tbf, nullptr,
      a2obf, nullptr, nullptr, nullptr, 1024, 1024, 1024, 1024, TT, TD, TD);
  // wo split-K (512-thr): z=0 -> a2pb, z=1 -> a2pb + woDelta (= Sbf)
  k_wo512<<<dim3(8, 32, 2), dim3(512), 0, stream>>>(a2obf, w_wot, a2pb, woDelta);
  k_combine<<<NTz, blk, 0, stream>>>(x2b, hbf, eofb, eofb2, a2pb, a2pb2, rout,
      conv_w, tg, sinkp, outx);
}